// Round 2
// baseline (537.802 us; speedup 1.0000x reference)
//
#include <hip/hip_runtime.h>

#define BH   512
#define NW   256
#define CC   128
#define TOK  (BH * NW)   // 131072 tokens per side

typedef __attribute__((ext_vector_type(8))) short short8;
typedef __attribute__((ext_vector_type(4))) float f32x4;
typedef __attribute__((ext_vector_type(4))) int   i32x4;
typedef __attribute__((ext_vector_type(4))) unsigned short us4;
typedef __attribute__((ext_vector_type(2))) unsigned int u32x2;
typedef unsigned short ushort_t;

static __device__ __forceinline__ f32x4 mfma16(short8 a, short8 b, f32x4 c) {
    return __builtin_amdgcn_mfma_f32_16x16x32_bf16(a, b, c, 0, 0, 0);
}

// float -> bf16 bits, round-to-nearest-even
static __device__ __forceinline__ ushort_t f2bf(float f) {
    unsigned int u = __float_as_uint(f);
    u = (u + 0x7fffu + ((u >> 16) & 1u)) >> 16;
    return (ushort_t)u;
}
static __device__ __forceinline__ unsigned int pk2(float a, float b) {
    return (unsigned int)f2bf(a) | ((unsigned int)f2bf(b) << 16);
}

// ---------------------------------------------------------------------------
// Kernel 0: convert projection weights f32 -> bf16 into a scratch region
// (placed at the start of d_out; k_ln_proj reads it, k_attn later overwrites).
// ---------------------------------------------------------------------------
__global__ __launch_bounds__(256)
void k_prep(const float* __restrict__ WpL, const float* __restrict__ WpR,
            ushort_t* __restrict__ Wb)   // [2][256][128] bf16
{
    int e = (blockIdx.x * 256 + threadIdx.x) * 4;   // 0..65532
    const float* src = (e < 32768) ? (WpL + e) : (WpR + e - 32768);
    float4 v = *(const float4*)src;
    us4 o;
    o[0] = f2bf(v.x); o[1] = f2bf(v.y); o[2] = f2bf(v.z); o[3] = f2bf(v.w);
    *(us4*)(Wb + e) = o;
}

// ---------------------------------------------------------------------------
// Kernel 1: fused LayerNorm + KV projection.
//   kv[token][0..255] = LN(feat[token]) @ Wp^T + bp   (bf16)
//   l_k half (side 0, features<128) pre-scaled by 0.1 (attention scale fold).
//   grid: (2048 m-tiles of 64 tokens, 2 n-halves, 2 sides), 256 thr.
//   B fragments read directly from global bf16 W (L1-resident).
// ---------------------------------------------------------------------------
__global__ __launch_bounds__(256, 6)
void k_ln_proj(const float* __restrict__ featL, const float* __restrict__ featR,
               const ushort_t* __restrict__ Wb,
               const float* __restrict__ bL,    const float* __restrict__ bR,
               const float* __restrict__ nw,    const float* __restrict__ nb,
               ushort_t* __restrict__ kvL,      ushort_t* __restrict__ kvR)
{
    const int side = blockIdx.z;
    const float* feat = side ? featR : featL;
    const ushort_t* W = Wb + side * 32768;          // [256][128] bf16
    const float* bp   = side ? bR : bL;
    ushort_t*    kv   = side ? kvR : kvL;

    const int m0 = blockIdx.x * 64;
    const int n0 = blockIdx.y * 128;

    __shared__ ushort_t Asm[64][136];               // LN'd activations (bf16)

    const int tid = threadIdx.x;

    // ---- LayerNorm: 8 threads/row, 16 elems each, 2 passes of 32 rows ----
    {
        const int q = tid & 7;
        const int r = tid >> 3;                     // 0..31
        float nwr[16], nbr[16];
#pragma unroll
        for (int i = 0; i < 4; ++i) {
            float4 a = *(const float4*)(nw + q * 16 + i * 4);
            float4 b = *(const float4*)(nb + q * 16 + i * 4);
            nwr[i*4+0]=a.x; nwr[i*4+1]=a.y; nwr[i*4+2]=a.z; nwr[i*4+3]=a.w;
            nbr[i*4+0]=b.x; nbr[i*4+1]=b.y; nbr[i*4+2]=b.z; nbr[i*4+3]=b.w;
        }
#pragma unroll
        for (int p = 0; p < 2; ++p) {
            const int row = p * 32 + r;
            const float* fr = feat + (size_t)(m0 + row) * CC + q * 16;
            float x[16];
            float s = 0.f, s2 = 0.f;
#pragma unroll
            for (int i = 0; i < 4; ++i) {
                float4 v = *(const float4*)(fr + i * 4);
                x[i*4+0]=v.x; x[i*4+1]=v.y; x[i*4+2]=v.z; x[i*4+3]=v.w;
                s  += v.x + v.y + v.z + v.w;
                s2 += v.x*v.x + v.y*v.y + v.z*v.z + v.w*v.w;
            }
#pragma unroll
            for (int m = 1; m < 8; m <<= 1) { s += __shfl_xor(s, m); s2 += __shfl_xor(s2, m); }
            float mu   = s * (1.f / 128.f);
            float var  = s2 * (1.f / 128.f) - mu * mu;
            float rstd = rsqrtf(var + 1e-5f);
            short8 o0, o1;
#pragma unroll
            for (int i = 0; i < 8; ++i) {
                o0[i] = (short)f2bf((x[i]     - mu) * rstd * nwr[i]     + nbr[i]);
                o1[i] = (short)f2bf((x[i + 8] - mu) * rstd * nwr[i + 8] + nbr[i + 8]);
            }
            *(short8*)&Asm[row][q * 16]     = o0;
            *(short8*)&Asm[row][q * 16 + 8] = o1;
        }
    }
    __syncthreads();

    // ---- MFMA: 4 waves = 2m x 2n, wave tile 32x64 ----
    const int wid = tid >> 6, lane = tid & 63, l16 = lane & 15, lh = lane >> 4;
    const int wm = (wid >> 1) * 32;
    const int wn = (wid & 1) * 64;
    f32x4 acc[2][4];
#pragma unroll
    for (int tr = 0; tr < 2; ++tr)
#pragma unroll
        for (int tn = 0; tn < 4; ++tn)
            acc[tr][tn] = (f32x4){0.f, 0.f, 0.f, 0.f};

#pragma unroll
    for (int kk = 0; kk < 4; ++kk) {
        short8 a[2];
#pragma unroll
        for (int tr = 0; tr < 2; ++tr)
            a[tr] = *(const short8*)&Asm[wm + tr*16 + l16][kk*32 + lh*8];
#pragma unroll
        for (int tn = 0; tn < 4; ++tn) {
            short8 b = *(const short8*)(W + (size_t)(n0 + wn + tn*16 + l16) * CC + kk*32 + lh*8);
#pragma unroll
            for (int tr = 0; tr < 2; ++tr)
                acc[tr][tn] = mfma16(b, a[tr], acc[tr][tn]);   // col(l16)=token, row(lh*4+j)=feature
        }
    }

    const float kscale = (side == 0 && n0 == 0) ? 0.1f : 1.0f;
#pragma unroll
    for (int tr = 0; tr < 2; ++tr)
#pragma unroll
        for (int tn = 0; tn < 4; ++tn) {
            const int f0 = n0 + wn + tn*16 + lh*4;
            const int token = m0 + wm + tr*16 + l16;
            float4 b4 = *(const float4*)(bp + f0);
            const float bb[4] = {b4.x, b4.y, b4.z, b4.w};
            us4 o;
#pragma unroll
            for (int j = 0; j < 4; ++j)
                o[j] = f2bf((acc[tr][tn][j] + bb[j]) * kscale);
            *(us4*)(kv + (size_t)token * 256 + f0) = o;
        }
}

// ---------------------------------------------------------------------------
// Kernel 2: attention, both directions (blockIdx.y).
//   S[w,v] = kA[w,:].kB[v,:]   (0.1 pre-folded into l_k)
//   P = softmax_v(S); out[w,:] = P @ V(B-side)
//   One block per (n, head, dir); 8 waves, each owns a 32-row w-stripe.
//   Online softmax over 4 v-chunks of 64 keeps S at 32 VGPRs/lane.
// ---------------------------------------------------------------------------
__global__ __launch_bounds__(512, 4)
void k_attn(const ushort_t* __restrict__ kvL, const ushort_t* __restrict__ kvR,
            float* __restrict__ outBase)
{
    const int dir = blockIdx.y;
    const ushort_t* kvA = dir ? kvR : kvL;
    const ushort_t* kvB = dir ? kvL : kvR;
    float* out = outBase + (size_t)dir * TOK * CC;

    const int n = blockIdx.x >> 2;
    const int e = blockIdx.x & 3;
    const int tid = threadIdx.x;
    const int wid = tid >> 6, lane = tid & 63, l16 = lane & 15, lh = lane >> 4;
    const int W0 = wid * 32;

    __shared__ ushort_t vT[32][264];     // V transposed: [c][v]
    __shared__ ushort_t pL[8][32][40];   // wave-private P chunk [w][v_loc]

    // ---- issue V loads early (T14 async-stage) ----
    unsigned int uA[4], uB[4];
    int vps[4], cps[4];
#pragma unroll
    for (int u = 0; u < 4; ++u) {
        int unit = tid + u * 512;        // 2048 units = 16 c-pairs x 128 v-pairs
        int cp = unit & 15, vp = unit >> 4;
        vps[u] = vp * 2; cps[u] = cp * 2;
        const ushort_t* g = kvB + (size_t)(n * 256 + vp * 2) * 256 + 128 + e * 32 + cp * 2;
        uA[u] = *(const unsigned int*)g;
        uB[u] = *(const unsigned int*)(g + 256);
    }

    // ---- wave-private A fragments (kA rows) ----
    short8 aK[2];
#pragma unroll
    for (int tr = 0; tr < 2; ++tr)
        aK[tr] = *(const short8*)(kvA + (size_t)(n * 256 + W0 + tr*16 + l16) * 256 + e * 32 + lh * 8);

    f32x4 oacc[2][2];
#pragma unroll
    for (int tr = 0; tr < 2; ++tr)
#pragma unroll
        for (int ct = 0; ct < 2; ++ct)
            oacc[tr][ct] = (f32x4){0.f, 0.f, 0.f, 0.f};
    float mrun[2] = {-1e30f, -1e30f};
    float lrun[2] = {0.f, 0.f};

#pragma unroll
    for (int nc = 0; nc < 4; ++nc) {
        const int vc0 = nc * 64;

        // ---- QK chunk: S[w, vc0..vc0+63] ----
        short8 bk[4];
#pragma unroll
        for (int tc = 0; tc < 4; ++tc)
            bk[tc] = *(const short8*)(kvB + (size_t)(n * 256 + vc0 + tc*16 + l16) * 256 + e * 32 + lh * 8);
        f32x4 s[2][4];
#pragma unroll
        for (int tr = 0; tr < 2; ++tr)
#pragma unroll
            for (int tc = 0; tc < 4; ++tc)
                s[tr][tc] = (f32x4){0.f, 0.f, 0.f, 0.f};
#pragma unroll
        for (int tc = 0; tc < 4; ++tc) {
#pragma unroll
            for (int tr = 0; tr < 2; ++tr)
                s[tr][tc] = mfma16(bk[tc], aK[tr], s[tr][tc]);  // col(l16)=w, row(lh*4+j)=v
        }

        // ---- online softmax (over v) ----
        float corr[2];
#pragma unroll
        for (int tr = 0; tr < 2; ++tr) {
            float cm = -1e30f;
#pragma unroll
            for (int tc = 0; tc < 4; ++tc)
#pragma unroll
                for (int j = 0; j < 4; ++j) cm = fmaxf(cm, s[tr][tc][j]);
            cm = fmaxf(cm, __shfl_xor(cm, 16));
            cm = fmaxf(cm, __shfl_xor(cm, 32));
            float mn = fmaxf(mrun[tr], cm);
            corr[tr] = __expf(mrun[tr] - mn);
            float cs = 0.f;
#pragma unroll
            for (int tc = 0; tc < 4; ++tc)
#pragma unroll
                for (int j = 0; j < 4; ++j) {
                    float p = __expf(s[tr][tc][j] - mn);
                    s[tr][tc][j] = p;
                    cs += p;
                }
            cs += __shfl_xor(cs, 16);
            cs += __shfl_xor(cs, 32);
            lrun[tr] = lrun[tr] * corr[tr] + cs;
            mrun[tr] = mn;
#pragma unroll
            for (int ct = 0; ct < 2; ++ct)
#pragma unroll
                for (int j = 0; j < 4; ++j)
                    oacc[tr][ct][j] *= corr[tr];
        }

        // ---- after chunk-0 softmax: commit V to LDS, single barrier ----
        if (nc == 0) {
#pragma unroll
            for (int u = 0; u < 4; ++u) {
                unsigned int w0 = (uA[u] & 0xffffu) | (uB[u] << 16);
                unsigned int w1 = (uA[u] >> 16) | (uB[u] & 0xffff0000u);
                *(unsigned int*)&vT[cps[u]    ][vps[u]] = w0;
                *(unsigned int*)&vT[cps[u] + 1][vps[u]] = w1;
            }
            __syncthreads();
        }

        // ---- PV: two 32-wide k-slices, P staged in wave-private LDS ----
#pragma unroll
        for (int ks = 0; ks < 2; ++ks) {
#pragma unroll
            for (int tr = 0; tr < 2; ++tr)
#pragma unroll
                for (int th = 0; th < 2; ++th) {
                    int tc = ks * 2 + th;
                    u32x2 w;
                    w[0] = pk2(s[tr][tc][0], s[tr][tc][1]);
                    w[1] = pk2(s[tr][tc][2], s[tr][tc][3]);
                    *(u32x2*)&pL[wid][tr*16 + l16][th*16 + lh*4] = w;
                }
            short8 aP[2], bV[2];
#pragma unroll
            for (int tr = 0; tr < 2; ++tr)
                aP[tr] = *(const short8*)&pL[wid][tr*16 + l16][lh*8];
#pragma unroll
            for (int ct = 0; ct < 2; ++ct)
                bV[ct] = *(const short8*)&vT[ct*16 + l16][vc0 + ks*32 + lh*8];
#pragma unroll
            for (int tr = 0; tr < 2; ++tr)
#pragma unroll
                for (int ct = 0; ct < 2; ++ct)
                    oacc[tr][ct] = mfma16(bV[ct], aP[tr], oacc[tr][ct]); // col=w, row=c
        }
    }

    // ---- normalize + float4 stores ----
#pragma unroll
    for (int tr = 0; tr < 2; ++tr) {
        float rinv = 1.f / lrun[tr];
        const size_t rowoff = (size_t)(n * 256 + W0 + tr*16 + l16) * CC + e * 32;
#pragma unroll
        for (int ct = 0; ct < 2; ++ct) {
            float4 o;
            o.x = oacc[tr][ct][0] * rinv;
            o.y = oacc[tr][ct][1] * rinv;
            o.z = oacc[tr][ct][2] * rinv;
            o.w = oacc[tr][ct][3] * rinv;
            *(float4*)(out + rowoff + ct*16 + lh*4) = o;
        }
    }
}

// ---------------------------------------------------------------------------
// Kernel 3: out projection + bias + residual, in-place on d_out half.
// ---------------------------------------------------------------------------
__global__ __launch_bounds__(512, 4)
void k_outproj(float* __restrict__ outBase,
               const float* __restrict__ featL, const float* __restrict__ featR,
               const float* __restrict__ WoL,   const float* __restrict__ WoR,
               const float* __restrict__ boL,   const float* __restrict__ boR)
{
    const int side = blockIdx.y;
    float* io = outBase + (size_t)side * TOK * CC;
    const float* feat = side ? featR : featL;
    const float* Wo   = side ? WoR   : WoL;
    const float* bo   = side ? boR   : boL;

    const int m0 = blockIdx.x * 64;
    const int tid = threadIdx.x;

    __shared__ ushort_t Asm[64][136];
    __shared__ ushort_t Wsm[128][136];

#pragma unroll
    for (int i = 0; i < 8; ++i) {
        int u = tid + i * 512;
        int r = u >> 5, c4 = (u & 31) * 4;
        float4 w4 = *(const float4*)(Wo + (size_t)r * CC + c4);
        Wsm[r][c4+0] = f2bf(w4.x); Wsm[r][c4+1] = f2bf(w4.y);
        Wsm[r][c4+2] = f2bf(w4.z); Wsm[r][c4+3] = f2bf(w4.w);
    }
#pragma unroll
    for (int i = 0; i < 4; ++i) {
        int u = tid + i * 512;
        int r = u >> 5, c4 = (u & 31) * 4;
        float4 a4 = *(const float4*)(io + (size_t)(m0 + r) * CC + c4);
        Asm[r][c4+0] = f2bf(a4.x); Asm[r][c4+1] = f2bf(a4.y);
        Asm[r][c4+2] = f2bf(a4.z); Asm[r][c4+3] = f2bf(a4.w);
    }
    __syncthreads();

    const int wid = tid >> 6, lane = tid & 63, l16 = lane & 15, lh = lane >> 4;
    const int wm = (wid >> 2) * 32;
    const int wn = (wid & 3) * 32;
    f32x4 acc[2][2];
#pragma unroll
    for (int tr = 0; tr < 2; ++tr)
#pragma unroll
        for (int nt = 0; nt < 2; ++nt)
            acc[tr][nt] = (f32x4){0.f, 0.f, 0.f, 0.f};

#pragma unroll
    for (int kk = 0; kk < 4; ++kk) {
        short8 a[2], b[2];
#pragma unroll
        for (int tr = 0; tr < 2; ++tr)
            a[tr] = *(const short8*)&Asm[wm + tr*16 + l16][kk*32 + lh*8];
#pragma unroll
        for (int nt = 0; nt < 2; ++nt)
            b[nt] = *(const short8*)&Wsm[wn + nt*16 + l16][kk*32 + lh*8];
#pragma unroll
        for (int tr = 0; tr < 2; ++tr)
#pragma unroll
            for (int nt = 0; nt < 2; ++nt)
                acc[tr][nt] = mfma16(a[tr], b[nt], acc[tr][nt]);
    }

#pragma unroll
    for (int tr = 0; tr < 2; ++tr)
#pragma unroll
        for (int nt = 0; nt < 2; ++nt) {
            int c = wn + nt*16 + l16;
            float bias = bo[c];
#pragma unroll
            for (int j = 0; j < 4; ++j) {
                int r = m0 + wm + tr*16 + lh*4 + j;
                io[(size_t)r * CC + c] = acc[tr][nt][j] + bias + feat[(size_t)r * CC + c];
            }
        }
}

// ---------------------------------------------------------------------------
extern "C" void kernel_launch(void* const* d_in, const int* in_sizes, int n_in,
                              void* d_out, int out_size, void* d_ws, size_t ws_size,
                              hipStream_t stream)
{
    const float* featL = (const float*)d_in[0];
    const float* featR = (const float*)d_in[1];
    const float* WpL   = (const float*)d_in[2];
    const float* WpR   = (const float*)d_in[3];
    const float* bpL   = (const float*)d_in[4];
    const float* bpR   = (const float*)d_in[5];
    const float* WoL   = (const float*)d_in[6];
    const float* boL   = (const float*)d_in[7];
    const float* WoR   = (const float*)d_in[8];
    const float* boR   = (const float*)d_in[9];
    const float* nw    = (const float*)d_in[10];
    const float* nb    = (const float*)d_in[11];

    float* out = (float*)d_out;
    ushort_t* kvL = (ushort_t*)d_ws;                 // [TOK][256] bf16
    ushort_t* kvR = kvL + (size_t)TOK * 256;         // [TOK][256] bf16
    ushort_t* Wb  = (ushort_t*)d_out;                // temp: [2][256][128] bf16,
                                                     // overwritten by k_attn

    k_prep<<<dim3(64), 256, 0, stream>>>(WpL, WpR, Wb);
    k_ln_proj<<<dim3(2048, 2, 2), 256, 0, stream>>>(featL, featR, Wb,
                                                    bpL, bpR, nw, nb, kvL, kvR);
    k_attn<<<dim3(BH * 4, 2), 512, 0, stream>>>(kvL, kvR, out);
    k_outproj<<<dim3(TOK / 64, 2), 512, 0, stream>>>(out, featL, featR,
                                                     WoL, WoR, boL, boR);
}

// Round 3
// 314.518 us; speedup vs baseline: 1.7099x; 1.7099x over previous
//
#include <hip/hip_runtime.h>

#define BH   512
#define NW   256
#define CC   128
#define TOK  (BH * NW)   // 131072 tokens per side

typedef __attribute__((ext_vector_type(8))) short short8;
typedef __attribute__((ext_vector_type(4))) float f32x4;
typedef __attribute__((ext_vector_type(4))) int   i32x4;
typedef __attribute__((ext_vector_type(4))) unsigned short us4;
typedef __attribute__((ext_vector_type(2))) unsigned int u32x2;
typedef unsigned short ushort_t;

static __device__ __forceinline__ f32x4 mfma16(short8 a, short8 b, f32x4 c) {
    return __builtin_amdgcn_mfma_f32_16x16x32_bf16(a, b, c, 0, 0, 0);
}

// float -> bf16 bits, round-to-nearest-even
static __device__ __forceinline__ ushort_t f2bf(float f) {
    unsigned int u = __float_as_uint(f);
    u = (u + 0x7fffu + ((u >> 16) & 1u)) >> 16;
    return (ushort_t)u;
}
static __device__ __forceinline__ unsigned int pk2(float a, float b) {
    return (unsigned int)f2bf(a) | ((unsigned int)f2bf(b) << 16);
}

// ---------------------------------------------------------------------------
// Kernel 0: convert projection weights f32 -> bf16 into scratch at d_out
// (k_ln_proj reads it; k_attn later overwrites d_out).
// ---------------------------------------------------------------------------
__global__ __launch_bounds__(256)
void k_prep(const float* __restrict__ WpL, const float* __restrict__ WpR,
            ushort_t* __restrict__ Wb)   // [2][256][128] bf16
{
    int e = (blockIdx.x * 256 + threadIdx.x) * 4;   // 0..65532
    const float* src = (e < 32768) ? (WpL + e) : (WpR + e - 32768);
    float4 v = *(const float4*)src;
    us4 o;
    o[0] = f2bf(v.x); o[1] = f2bf(v.y); o[2] = f2bf(v.z); o[3] = f2bf(v.w);
    *(us4*)(Wb + e) = o;
}

// ---------------------------------------------------------------------------
// Kernel 1: fused LayerNorm + KV projection.
//   kv[token][0..255] = LN(feat[token]) @ Wp^T + bp   (bf16)
//   l_k half (side 0, features<128) pre-scaled by 0.1.
//   grid: (1024 m-tiles of 128 tokens, 2 sides), 512 thr.
//   LN once per tile; all 256 output features per block; W read direct (bf16).
// ---------------------------------------------------------------------------
__global__ __launch_bounds__(512, 2)
void k_ln_proj(const float* __restrict__ featL, const float* __restrict__ featR,
               const ushort_t* __restrict__ Wb,
               const float* __restrict__ bL,    const float* __restrict__ bR,
               const float* __restrict__ nw,    const float* __restrict__ nb,
               ushort_t* __restrict__ kvL,      ushort_t* __restrict__ kvR)
{
    const int side = blockIdx.y;
    const float* feat = side ? featR : featL;
    const ushort_t* W = Wb + side * 32768;          // [256][128] bf16
    const float* bp   = side ? bR : bL;
    ushort_t*    kv   = side ? kvR : kvL;

    const int m0 = blockIdx.x * 128;
    const int tid = threadIdx.x;

    __shared__ ushort_t Asm[128][136];
    __shared__ float    nwb[2][128];

    if (tid < 128) { nwb[0][tid] = nw[tid]; nwb[1][tid] = nb[tid]; }
    __syncthreads();

    // ---- LayerNorm: 4 threads/row, 32 elems each ----
    {
        const int row = tid >> 2;
        const int q   = tid & 3;
        const float* fr = feat + (size_t)(m0 + row) * CC + q * 32;
        float x[32];
        float s = 0.f, s2 = 0.f;
#pragma unroll
        for (int i = 0; i < 8; ++i) {
            float4 v = *(const float4*)(fr + i * 4);
            x[i*4+0]=v.x; x[i*4+1]=v.y; x[i*4+2]=v.z; x[i*4+3]=v.w;
            s  += v.x + v.y + v.z + v.w;
            s2 += v.x*v.x + v.y*v.y + v.z*v.z + v.w*v.w;
        }
#pragma unroll
        for (int m = 1; m < 4; m <<= 1) { s += __shfl_xor(s, m); s2 += __shfl_xor(s2, m); }
        float mu   = s * (1.f / 128.f);
        float var  = s2 * (1.f / 128.f) - mu * mu;
        float rstd = rsqrtf(var + 1e-5f);
#pragma unroll
        for (int h = 0; h < 4; ++h) {
            short8 o;
#pragma unroll
            for (int i = 0; i < 8; ++i) {
                int c = q * 32 + h * 8 + i;
                o[i] = (short)f2bf((x[h*8+i] - mu) * rstd * nwb[0][c] + nwb[1][c]);
            }
            *(short8*)&Asm[row][q * 32 + h * 8] = o;
        }
    }
    __syncthreads();

    // ---- MFMA: 8 waves = 4m x 2n, wave tile 32 tokens x 128 features ----
    const int wid = tid >> 6, lane = tid & 63, l16 = lane & 15, lh = lane >> 4;
    const int wm = (wid >> 1) * 32;
    const int wn = (wid & 1) * 128;
    f32x4 acc[2][8];
#pragma unroll
    for (int tr = 0; tr < 2; ++tr)
#pragma unroll
        for (int tn = 0; tn < 8; ++tn)
            acc[tr][tn] = (f32x4){0.f, 0.f, 0.f, 0.f};

#pragma unroll
    for (int kk = 0; kk < 4; ++kk) {
        short8 a[2];
#pragma unroll
        for (int tr = 0; tr < 2; ++tr)
            a[tr] = *(const short8*)&Asm[wm + tr*16 + l16][kk*32 + lh*8];
#pragma unroll
        for (int tn = 0; tn < 8; ++tn) {
            short8 b = *(const short8*)(W + (size_t)(wn + tn*16 + l16) * CC + kk*32 + lh*8);
#pragma unroll
            for (int tr = 0; tr < 2; ++tr)
                acc[tr][tn] = mfma16(b, a[tr], acc[tr][tn]);   // col(l16)=token, row=feature
        }
    }

    const float kscale = (side == 0 && wn == 0) ? 0.1f : 1.0f;
#pragma unroll
    for (int tr = 0; tr < 2; ++tr)
#pragma unroll
        for (int tn = 0; tn < 8; ++tn) {
            const int f0 = wn + tn*16 + lh*4;
            const int token = m0 + wm + tr*16 + l16;
            float4 b4 = *(const float4*)(bp + f0);
            const float bb[4] = {b4.x, b4.y, b4.z, b4.w};
            us4 o;
#pragma unroll
            for (int j = 0; j < 4; ++j)
                o[j] = f2bf((acc[tr][tn][j] + bb[j]) * kscale);
            *(us4*)(kv + (size_t)token * 256 + f0) = o;
        }
}

// ---------------------------------------------------------------------------
// Kernel 2: attention, one (n, head, dir) per block; 8 waves x 32-row stripes.
//   Online softmax over 8 v-chunks of 32; kB + vT staged in LDS; kA direct.
//   Chunked block swizzle keeps (dir0,dir1) of same (n,e) on one XCD.
// ---------------------------------------------------------------------------
__global__ __launch_bounds__(512, 2)
void k_attn(const ushort_t* __restrict__ kvL, const ushort_t* __restrict__ kvR,
            float* __restrict__ outBase)
{
    const int bx   = blockIdx.x;
    const int work = (bx & 7) * 512 + (bx >> 3);    // 4096 = 8 chunks x 512
    const int n    = work >> 3;
    const int e    = (work >> 1) & 3;
    const int dir  = work & 1;
    const ushort_t* kvA = dir ? kvR : kvL;
    const ushort_t* kvB = dir ? kvL : kvR;
    float* out = outBase + (size_t)dir * TOK * CC;

    const int tid = threadIdx.x;
    const int wid = tid >> 6, lane = tid & 63, l16 = lane & 15, lh = lane >> 4;
    const int W0 = wid * 32;

    __shared__ ushort_t kB[256][40];     // keys of B side (head slice)
    __shared__ ushort_t vT[32][274];     // V transposed [c][v], pad=274: 2-way-free
    __shared__ ushort_t pL[8][32][40];   // wave-private P chunk

    // ---- stage kB (256x32 bf16, coalesced 64B lines) ----
    {
        const ushort_t* src = kvB + (size_t)n * 256 * 256 + e * 32;
#pragma unroll
        for (int p = 0; p < 2; ++p) {
            int u = tid + p * 512;
            int r = u >> 2, c0 = (u & 3) * 8;
            *(i32x4*)&kB[r][c0] = *(const i32x4*)(src + (size_t)r * 256 + c0);
        }
    }
    // ---- stage vT (transpose via u32 repack; 2-way-free LDS writes) ----
    {
        const ushort_t* src = kvB + (size_t)n * 256 * 256 + 128 + e * 32;
#pragma unroll
        for (int u4 = 0; u4 < 4; ++u4) {
            int unit = tid + u4 * 512;              // 2048 = 16 c-pairs x 128 v-pairs
            int cp = unit & 15, vp = unit >> 4;
            unsigned int w0 = *(const unsigned int*)(src + (size_t)(vp*2    ) * 256 + cp*2);
            unsigned int w1 = *(const unsigned int*)(src + (size_t)(vp*2 + 1) * 256 + cp*2);
            *(unsigned int*)&vT[cp*2    ][vp*2] = (w0 & 0xffffu) | (w1 << 16);
            *(unsigned int*)&vT[cp*2 + 1][vp*2] = (w0 >> 16) | (w1 & 0xffff0000u);
        }
    }
    // ---- kA fragments direct from global (one 64B line per row) ----
    short8 aK[2];
#pragma unroll
    for (int tr = 0; tr < 2; ++tr)
        aK[tr] = *(const short8*)(kvA + (size_t)(n*256 + W0 + tr*16 + l16) * 256 + e*32 + lh*8);

    __syncthreads();

    f32x4 oacc[2][2];
#pragma unroll
    for (int tr = 0; tr < 2; ++tr)
#pragma unroll
        for (int ct = 0; ct < 2; ++ct)
            oacc[tr][ct] = (f32x4){0.f, 0.f, 0.f, 0.f};
    float mrun[2] = {-1e30f, -1e30f};
    float lrun[2] = {0.f, 0.f};

#pragma unroll 2
    for (int nc = 0; nc < 8; ++nc) {
        const int vc0 = nc * 32;

        // ---- QK chunk: S[w, vc0..vc0+31] ----
        short8 bk0 = *(const short8*)&kB[vc0      + l16][lh*8];
        short8 bk1 = *(const short8*)&kB[vc0 + 16 + l16][lh*8];
        f32x4 s[2][2];
#pragma unroll
        for (int tr = 0; tr < 2; ++tr) {
            s[tr][0] = mfma16(bk0, aK[tr], (f32x4){0.f,0.f,0.f,0.f});
            s[tr][1] = mfma16(bk1, aK[tr], (f32x4){0.f,0.f,0.f,0.f});
        }

        // ---- online softmax over v (w = l16, reduce over lh via shfl) ----
#pragma unroll
        for (int tr = 0; tr < 2; ++tr) {
            float cm = -1e30f;
#pragma unroll
            for (int tc = 0; tc < 2; ++tc)
#pragma unroll
                for (int j = 0; j < 4; ++j) cm = fmaxf(cm, s[tr][tc][j]);
            cm = fmaxf(cm, __shfl_xor(cm, 16));
            cm = fmaxf(cm, __shfl_xor(cm, 32));
            float mn = fmaxf(mrun[tr], cm);
            float corr = __expf(mrun[tr] - mn);
            float cs = 0.f;
#pragma unroll
            for (int tc = 0; tc < 2; ++tc)
#pragma unroll
                for (int j = 0; j < 4; ++j) {
                    float p = __expf(s[tr][tc][j] - mn);
                    s[tr][tc][j] = p;
                    cs += p;
                }
            cs += __shfl_xor(cs, 16);
            cs += __shfl_xor(cs, 32);
            lrun[tr] = lrun[tr] * corr + cs;
            mrun[tr] = mn;
#pragma unroll
            for (int ct = 0; ct < 2; ++ct)
#pragma unroll
                for (int j = 0; j < 4; ++j)
                    oacc[tr][ct][j] *= corr;

            // P chunk -> wave-private LDS (packed 8B writes)
#pragma unroll
            for (int tc = 0; tc < 2; ++tc) {
                u32x2 w;
                w[0] = pk2(s[tr][tc][0], s[tr][tc][1]);
                w[1] = pk2(s[tr][tc][2], s[tr][tc][3]);
                *(u32x2*)&pL[wid][tr*16 + l16][tc*16 + lh*4] = w;
            }
        }

        // ---- PV for this 32-wide k-slice ----
        short8 aP[2], bV[2];
#pragma unroll
        for (int tr = 0; tr < 2; ++tr)
            aP[tr] = *(const short8*)&pL[wid][tr*16 + l16][lh*8];
#pragma unroll
        for (int ct = 0; ct < 2; ++ct)
            bV[ct] = *(const short8*)&vT[ct*16 + l16][vc0 + lh*8];
#pragma unroll
        for (int tr = 0; tr < 2; ++tr)
#pragma unroll
            for (int ct = 0; ct < 2; ++ct)
                oacc[tr][ct] = mfma16(bV[ct], aP[tr], oacc[tr][ct]); // col=w, row=c
    }

    // ---- normalize + float4 stores (lanes {l,l+16,..} fill 64B lines) ----
#pragma unroll
    for (int tr = 0; tr < 2; ++tr) {
        float rinv = 1.f / lrun[tr];
        const size_t rowoff = (size_t)(n * 256 + W0 + tr*16 + l16) * CC + e * 32;
#pragma unroll
        for (int ct = 0; ct < 2; ++ct) {
            float4 o;
            o.x = oacc[tr][ct][0] * rinv;
            o.y = oacc[tr][ct][1] * rinv;
            o.z = oacc[tr][ct][2] * rinv;
            o.w = oacc[tr][ct][3] * rinv;
            *(float4*)(out + rowoff + ct*16 + lh*4) = o;
        }
    }
}

// ---------------------------------------------------------------------------
// Kernel 3: out projection + bias + residual, in-place on d_out half.
// ---------------------------------------------------------------------------
__global__ __launch_bounds__(512, 4)
void k_outproj(float* __restrict__ outBase,
               const float* __restrict__ featL, const float* __restrict__ featR,
               const float* __restrict__ WoL,   const float* __restrict__ WoR,
               const float* __restrict__ boL,   const float* __restrict__ boR)
{
    const int side = blockIdx.y;
    float* io = outBase + (size_t)side * TOK * CC;
    const float* feat = side ? featR : featL;
    const float* Wo   = side ? WoR   : WoL;
    const float* bo   = side ? boR   : boL;

    const int m0 = blockIdx.x * 64;
    const int tid = threadIdx.x;

    __shared__ ushort_t Asm[64][136];
    __shared__ ushort_t Wsm[128][136];

#pragma unroll
    for (int i = 0; i < 8; ++i) {
        int u = tid + i * 512;
        int r = u >> 5, c4 = (u & 31) * 4;
        float4 w4 = *(const float4*)(Wo + (size_t)r * CC + c4);
        Wsm[r][c4+0] = f2bf(w4.x); Wsm[r][c4+1] = f2bf(w4.y);
        Wsm[r][c4+2] = f2bf(w4.z); Wsm[r][c4+3] = f2bf(w4.w);
    }
#pragma unroll
    for (int i = 0; i < 4; ++i) {
        int u = tid + i * 512;
        int r = u >> 5, c4 = (u & 31) * 4;
        float4 a4 = *(const float4*)(io + (size_t)(m0 + r) * CC + c4);
        Asm[r][c4+0] = f2bf(a4.x); Asm[r][c4+1] = f2bf(a4.y);
        Asm[r][c4+2] = f2bf(a4.z); Asm[r][c4+3] = f2bf(a4.w);
    }
    __syncthreads();

    const int wid = tid >> 6, lane = tid & 63, l16 = lane & 15, lh = lane >> 4;
    const int wm = (wid >> 2) * 32;
    const int wn = (wid & 3) * 32;
    f32x4 acc[2][2];
#pragma unroll
    for (int tr = 0; tr < 2; ++tr)
#pragma unroll
        for (int nt = 0; nt < 2; ++nt)
            acc[tr][nt] = (f32x4){0.f, 0.f, 0.f, 0.f};

#pragma unroll
    for (int kk = 0; kk < 4; ++kk) {
        short8 a[2], b[2];
#pragma unroll
        for (int tr = 0; tr < 2; ++tr)
            a[tr] = *(const short8*)&Asm[wm + tr*16 + l16][kk*32 + lh*8];
#pragma unroll
        for (int nt = 0; nt < 2; ++nt)
            b[nt] = *(const short8*)&Wsm[wn + nt*16 + l16][kk*32 + lh*8];
#pragma unroll
        for (int tr = 0; tr < 2; ++tr)
#pragma unroll
            for (int nt = 0; nt < 2; ++nt)
                acc[tr][nt] = mfma16(a[tr], b[nt], acc[tr][nt]);
    }

#pragma unroll
    for (int tr = 0; tr < 2; ++tr)
#pragma unroll
        for (int nt = 0; nt < 2; ++nt) {
            int c = wn + nt*16 + l16;
            float bias = bo[c];
#pragma unroll
            for (int j = 0; j < 4; ++j) {
                int r = m0 + wm + tr*16 + lh*4 + j;
                io[(size_t)r * CC + c] = acc[tr][nt][j] + bias + feat[(size_t)r * CC + c];
            }
        }
}

// ---------------------------------------------------------------------------
extern "C" void kernel_launch(void* const* d_in, const int* in_sizes, int n_in,
                              void* d_out, int out_size, void* d_ws, size_t ws_size,
                              hipStream_t stream)
{
    const float* featL = (const float*)d_in[0];
    const float* featR = (const float*)d_in[1];
    const float* WpL   = (const float*)d_in[2];
    const float* WpR   = (const float*)d_in[3];
    const float* bpL   = (const float*)d_in[4];
    const float* bpR   = (const float*)d_in[5];
    const float* WoL   = (const float*)d_in[6];
    const float* boL   = (const float*)d_in[7];
    const float* WoR   = (const float*)d_in[8];
    const float* boR   = (const float*)d_in[9];
    const float* nw    = (const float*)d_in[10];
    const float* nb    = (const float*)d_in[11];

    float* out = (float*)d_out;
    ushort_t* kvL = (ushort_t*)d_ws;                 // [TOK][256] bf16
    ushort_t* kvR = kvL + (size_t)TOK * 256;         // [TOK][256] bf16
    ushort_t* Wb  = (ushort_t*)d_out;                // temp bf16 weights; k_attn overwrites

    k_prep<<<dim3(64), 256, 0, stream>>>(WpL, WpR, Wb);
    k_ln_proj<<<dim3(1024, 2), 512, 0, stream>>>(featL, featR, Wb,
                                                 bpL, bpR, nw, nb, kvL, kvR);
    k_attn<<<dim3(4096), 512, 0, stream>>>(kvL, kvR, out);
    k_outproj<<<dim3(TOK / 64, 2), 512, 0, stream>>>(out, featL, featR,
                                                     WoL, WoR, boL, boR);
}

// Round 4
// 263.580 us; speedup vs baseline: 2.0404x; 1.1933x over previous
//
#include <hip/hip_runtime.h>

#define BH   512
#define NW   256
#define CC   128
#define TOK  (BH * NW)   // 131072 tokens per side

typedef __attribute__((ext_vector_type(8))) short short8;
typedef __attribute__((ext_vector_type(4))) float f32x4;
typedef __attribute__((ext_vector_type(4))) int   i32x4;
typedef __attribute__((ext_vector_type(4))) unsigned short us4;
typedef __attribute__((ext_vector_type(2))) unsigned int u32x2;
typedef unsigned short ushort_t;

static __device__ __forceinline__ f32x4 mfma16(short8 a, short8 b, f32x4 c) {
    return __builtin_amdgcn_mfma_f32_16x16x32_bf16(a, b, c, 0, 0, 0);
}

// float -> bf16 bits, round-to-nearest-even
static __device__ __forceinline__ ushort_t f2bf(float f) {
    unsigned int u = __float_as_uint(f);
    u = (u + 0x7fffu + ((u >> 16) & 1u)) >> 16;
    return (ushort_t)u;
}
static __device__ __forceinline__ unsigned int pk2(float a, float b) {
    return (unsigned int)f2bf(a) | ((unsigned int)f2bf(b) << 16);
}

// ---------------------------------------------------------------------------
// Kernel 0: convert projection weights f32 -> bf16 into scratch at d_out
// (read by k_ln_proj; d_out later fully rewritten by attn/outproj).
// ---------------------------------------------------------------------------
__global__ __launch_bounds__(256)
void k_prep(const float* __restrict__ WpL, const float* __restrict__ WpR,
            ushort_t* __restrict__ Wb)   // [2][256][128] bf16
{
    int e = (blockIdx.x * 256 + threadIdx.x) * 4;   // 0..65532
    const float* src = (e < 32768) ? (WpL + e) : (WpR + e - 32768);
    float4 v = *(const float4*)src;
    us4 o;
    o[0] = f2bf(v.x); o[1] = f2bf(v.y); o[2] = f2bf(v.z); o[3] = f2bf(v.w);
    *(us4*)(Wb + e) = o;
}

// ---------------------------------------------------------------------------
// Kernel 1: fused LayerNorm + KV projection.
//   kv[token][0..255] = LN(feat[token]) @ Wp^T + bp   (bf16)
//   l_k half (side 0, features<128) pre-scaled by 0.1.
//   grid: (2048 m-tiles of 64 tokens, 2 sides), 256 thr = 4 waves.
//   Each wave owns a 64-feature slice; its W fragments (16 x short8 = 64 VGPR)
//   are loaded up-front so the MFMA loop reads only LDS + registers.
// ---------------------------------------------------------------------------
__global__ __launch_bounds__(256, 2)
void k_ln_proj(const float* __restrict__ featL, const float* __restrict__ featR,
               const ushort_t* __restrict__ Wb,
               const float* __restrict__ bL,    const float* __restrict__ bR,
               const float* __restrict__ nw,    const float* __restrict__ nb,
               ushort_t* __restrict__ kvL,      ushort_t* __restrict__ kvR)
{
    const int side = blockIdx.y;
    const float* feat = side ? featR : featL;
    const ushort_t* W = Wb + side * 32768;          // [256][128] bf16
    const float* bp   = side ? bR : bL;
    ushort_t*    kv   = side ? kvR : kvL;

    const int m0  = blockIdx.x * 64;
    const int tid = threadIdx.x;
    const int wid = tid >> 6, lane = tid & 63, l16 = lane & 15, lh = lane >> 4;
    const int wn  = wid * 64;                       // wave's feature slice

    __shared__ ushort_t Asm[64][136];
    __shared__ float    nwb[2][128];

    // ---- issue W-fragment + bias loads up-front (resolve under LN) ----
    short8 Bf[16];                                  // [kk][tn]
#pragma unroll
    for (int kk = 0; kk < 4; ++kk)
#pragma unroll
        for (int tn = 0; tn < 4; ++tn)
            Bf[kk*4 + tn] = *(const short8*)(W + (size_t)(wn + tn*16 + l16) * CC + kk*32 + lh*8);
    float4 bias[4];
#pragma unroll
    for (int tn = 0; tn < 4; ++tn)
        bias[tn] = *(const float4*)(bp + wn + tn*16 + lh*4);

    if (tid < 128) { nwb[0][tid] = nw[tid]; nwb[1][tid] = nb[tid]; }
    __syncthreads();

    // ---- LayerNorm: 4 threads/row, 32 elems each, 64 rows ----
    {
        const int row = tid >> 2;
        const int q   = tid & 3;
        const float* fr = feat + (size_t)(m0 + row) * CC + q * 32;
        float x[32];
        float s = 0.f, s2 = 0.f;
#pragma unroll
        for (int i = 0; i < 8; ++i) {
            float4 v = *(const float4*)(fr + i * 4);
            x[i*4+0]=v.x; x[i*4+1]=v.y; x[i*4+2]=v.z; x[i*4+3]=v.w;
            s  += v.x + v.y + v.z + v.w;
            s2 += v.x*v.x + v.y*v.y + v.z*v.z + v.w*v.w;
        }
#pragma unroll
        for (int m = 1; m < 4; m <<= 1) { s += __shfl_xor(s, m); s2 += __shfl_xor(s2, m); }
        float mu   = s * (1.f / 128.f);
        float var  = s2 * (1.f / 128.f) - mu * mu;
        float rstd = rsqrtf(var + 1e-5f);
#pragma unroll
        for (int h = 0; h < 4; ++h) {
            short8 o;
#pragma unroll
            for (int i = 0; i < 8; ++i) {
                int c = q * 32 + h * 8 + i;
                o[i] = (short)f2bf((x[h*8+i] - mu) * rstd * nwb[0][c] + nwb[1][c]);
            }
            *(short8*)&Asm[row][q * 32 + h * 8] = o;
        }
    }
    __syncthreads();

    // ---- MFMA: wave = 64 tokens x 64 features; A from LDS, B from regs ----
    f32x4 acc[4][4];                                // [m-tile][n-frag]
#pragma unroll
    for (int mt = 0; mt < 4; ++mt)
#pragma unroll
        for (int tn = 0; tn < 4; ++tn)
            acc[mt][tn] = (f32x4){0.f, 0.f, 0.f, 0.f};

#pragma unroll
    for (int kk = 0; kk < 4; ++kk) {
        short8 a[4];
#pragma unroll
        for (int mt = 0; mt < 4; ++mt)
            a[mt] = *(const short8*)&Asm[mt*16 + l16][kk*32 + lh*8];
#pragma unroll
        for (int tn = 0; tn < 4; ++tn)
#pragma unroll
            for (int mt = 0; mt < 4; ++mt)
                acc[mt][tn] = mfma16(Bf[kk*4 + tn], a[mt], acc[mt][tn]); // col=token, row=feat
    }

    const float kscale = (side == 0 && wn < 128) ? 0.1f : 1.0f;
#pragma unroll
    for (int mt = 0; mt < 4; ++mt)
#pragma unroll
        for (int tn = 0; tn < 4; ++tn) {
            const int f0 = wn + tn*16 + lh*4;
            const int token = m0 + mt*16 + l16;
            const float bb[4] = {bias[tn].x, bias[tn].y, bias[tn].z, bias[tn].w};
            us4 o;
#pragma unroll
            for (int j = 0; j < 4; ++j)
                o[j] = f2bf((acc[mt][tn][j] + bb[j]) * kscale);
            *(us4*)(kv + (size_t)token * 256 + f0) = o;
        }
}

// ---------------------------------------------------------------------------
// Kernel 2: attention, one (n, head, dir) per block; 8 waves x 32-row stripes.
//   Online softmax over 8 v-chunks of 32; kB + vT staged in LDS; kA direct.
//   BF16OUT: write bf16 to aout scratch, else f32 to d_out.
// ---------------------------------------------------------------------------
template<int BF16OUT>
__global__ __launch_bounds__(512, 2)
void k_attn(const ushort_t* __restrict__ kvL, const ushort_t* __restrict__ kvR,
            float* __restrict__ outFBase, ushort_t* __restrict__ outBBase)
{
    const int bx   = blockIdx.x;
    const int work = (bx & 7) * 512 + (bx >> 3);    // 4096 = 8 chunks x 512
    const int n    = work >> 3;
    const int e    = (work >> 1) & 3;
    const int dir  = work & 1;
    const ushort_t* kvA = dir ? kvR : kvL;
    const ushort_t* kvB = dir ? kvL : kvR;

    const int tid = threadIdx.x;
    const int wid = tid >> 6, lane = tid & 63, l16 = lane & 15, lh = lane >> 4;
    const int W0 = wid * 32;

    __shared__ ushort_t kB[256][40];     // keys of B side (head slice)
    __shared__ ushort_t vT[32][274];     // V transposed [c][v]
    __shared__ ushort_t pL[8][32][40];   // wave-private P chunk

    // ---- stage kB (256x32 bf16, coalesced 64B lines) ----
    {
        const ushort_t* src = kvB + (size_t)n * 256 * 256 + e * 32;
#pragma unroll
        for (int p = 0; p < 2; ++p) {
            int u = tid + p * 512;
            int r = u >> 2, c0 = (u & 3) * 8;
            *(i32x4*)&kB[r][c0] = *(const i32x4*)(src + (size_t)r * 256 + c0);
        }
    }
    // ---- stage vT (transpose via u32 repack) ----
    {
        const ushort_t* src = kvB + (size_t)n * 256 * 256 + 128 + e * 32;
#pragma unroll
        for (int u4 = 0; u4 < 4; ++u4) {
            int unit = tid + u4 * 512;              // 2048 = 16 c-pairs x 128 v-pairs
            int cp = unit & 15, vp = unit >> 4;
            unsigned int w0 = *(const unsigned int*)(src + (size_t)(vp*2    ) * 256 + cp*2);
            unsigned int w1 = *(const unsigned int*)(src + (size_t)(vp*2 + 1) * 256 + cp*2);
            *(unsigned int*)&vT[cp*2    ][vp*2] = (w0 & 0xffffu) | (w1 << 16);
            *(unsigned int*)&vT[cp*2 + 1][vp*2] = (w0 >> 16) | (w1 & 0xffff0000u);
        }
    }
    // ---- kA fragments direct from global ----
    short8 aK[2];
#pragma unroll
    for (int tr = 0; tr < 2; ++tr)
        aK[tr] = *(const short8*)(kvA + (size_t)(n*256 + W0 + tr*16 + l16) * 256 + e*32 + lh*8);

    __syncthreads();

    f32x4 oacc[2][2];
#pragma unroll
    for (int tr = 0; tr < 2; ++tr)
#pragma unroll
        for (int ct = 0; ct < 2; ++ct)
            oacc[tr][ct] = (f32x4){0.f, 0.f, 0.f, 0.f};
    float mrun[2] = {-1e30f, -1e30f};
    float lrun[2] = {0.f, 0.f};

#pragma unroll 2
    for (int nc = 0; nc < 8; ++nc) {
        const int vc0 = nc * 32;

        // ---- QK chunk: S[w, vc0..vc0+31] ----
        short8 bk0 = *(const short8*)&kB[vc0      + l16][lh*8];
        short8 bk1 = *(const short8*)&kB[vc0 + 16 + l16][lh*8];
        f32x4 s[2][2];
#pragma unroll
        for (int tr = 0; tr < 2; ++tr) {
            s[tr][0] = mfma16(bk0, aK[tr], (f32x4){0.f,0.f,0.f,0.f});
            s[tr][1] = mfma16(bk1, aK[tr], (f32x4){0.f,0.f,0.f,0.f});
        }

        // ---- online softmax over v (w = l16, reduce over lh via shfl) ----
#pragma unroll
        for (int tr = 0; tr < 2; ++tr) {
            float cm = -1e30f;
#pragma unroll
            for (int tc = 0; tc < 2; ++tc)
#pragma unroll
                for (int j = 0; j < 4; ++j) cm = fmaxf(cm, s[tr][tc][j]);
            cm = fmaxf(cm, __shfl_xor(cm, 16));
            cm = fmaxf(cm, __shfl_xor(cm, 32));
            float mn = fmaxf(mrun[tr], cm);
            float corr = __expf(mrun[tr] - mn);
            float cs = 0.f;
#pragma unroll
            for (int tc = 0; tc < 2; ++tc)
#pragma unroll
                for (int j = 0; j < 4; ++j) {
                    float p = __expf(s[tr][tc][j] - mn);
                    s[tr][tc][j] = p;
                    cs += p;
                }
            cs += __shfl_xor(cs, 16);
            cs += __shfl_xor(cs, 32);
            lrun[tr] = lrun[tr] * corr + cs;
            mrun[tr] = mn;
#pragma unroll
            for (int ct = 0; ct < 2; ++ct)
#pragma unroll
                for (int j = 0; j < 4; ++j)
                    oacc[tr][ct][j] *= corr;

#pragma unroll
            for (int tc = 0; tc < 2; ++tc) {
                u32x2 w;
                w[0] = pk2(s[tr][tc][0], s[tr][tc][1]);
                w[1] = pk2(s[tr][tc][2], s[tr][tc][3]);
                *(u32x2*)&pL[wid][tr*16 + l16][tc*16 + lh*4] = w;
            }
        }

        // ---- PV for this 32-wide k-slice ----
        short8 aP[2], bV[2];
#pragma unroll
        for (int tr = 0; tr < 2; ++tr)
            aP[tr] = *(const short8*)&pL[wid][tr*16 + l16][lh*8];
#pragma unroll
        for (int ct = 0; ct < 2; ++ct)
            bV[ct] = *(const short8*)&vT[ct*16 + l16][vc0 + lh*8];
#pragma unroll
        for (int tr = 0; tr < 2; ++tr)
#pragma unroll
            for (int ct = 0; ct < 2; ++ct)
                oacc[tr][ct] = mfma16(bV[ct], aP[tr], oacc[tr][ct]); // col=w, row=c
    }

    // ---- normalize + store ----
#pragma unroll
    for (int tr = 0; tr < 2; ++tr) {
        float rinv = 1.f / lrun[tr];
        const int token = n * 256 + W0 + tr*16 + l16;
        if (BF16OUT) {
            ushort_t* outB = outBBase + (size_t)dir * TOK * CC;
#pragma unroll
            for (int ct = 0; ct < 2; ++ct) {
                us4 o;
#pragma unroll
                for (int j = 0; j < 4; ++j)
                    o[j] = f2bf(oacc[tr][ct][j] * rinv);
                *(us4*)(outB + (size_t)token * CC + e*32 + ct*16 + lh*4) = o;
            }
        } else {
            float* outF = outFBase + (size_t)dir * TOK * CC;
#pragma unroll
            for (int ct = 0; ct < 2; ++ct) {
                float4 o;
                o.x = oacc[tr][ct][0] * rinv;
                o.y = oacc[tr][ct][1] * rinv;
                o.z = oacc[tr][ct][2] * rinv;
                o.w = oacc[tr][ct][3] * rinv;
                *(float4*)(outF + (size_t)token * CC + e*32 + ct*16 + lh*4) = o;
            }
        }
    }
}

// ---------------------------------------------------------------------------
// Kernel 3: out projection + bias + residual -> d_out (f32).
//   BF16IN: attention output read from bf16 scratch, else f32 in d_out.
// ---------------------------------------------------------------------------
template<int BF16IN>
__global__ __launch_bounds__(512, 4)
void k_outproj(float* __restrict__ outBase, const ushort_t* __restrict__ aoutBase,
               const float* __restrict__ featL, const float* __restrict__ featR,
               const float* __restrict__ WoL,   const float* __restrict__ WoR,
               const float* __restrict__ boL,   const float* __restrict__ boR)
{
    const int side = blockIdx.y;
    float* io = outBase + (size_t)side * TOK * CC;
    const float* feat = side ? featR : featL;
    const float* Wo   = side ? WoR   : WoL;
    const float* bo   = side ? boR   : boL;

    const int m0 = blockIdx.x * 64;
    const int tid = threadIdx.x;

    __shared__ ushort_t Asm[64][136];
    __shared__ ushort_t Wsm[128][136];

#pragma unroll
    for (int i = 0; i < 8; ++i) {
        int u = tid + i * 512;
        int r = u >> 5, c4 = (u & 31) * 4;
        float4 w4 = *(const float4*)(Wo + (size_t)r * CC + c4);
        Wsm[r][c4+0] = f2bf(w4.x); Wsm[r][c4+1] = f2bf(w4.y);
        Wsm[r][c4+2] = f2bf(w4.z); Wsm[r][c4+3] = f2bf(w4.w);
    }
    if (BF16IN) {
        const ushort_t* src = aoutBase + (size_t)side * TOK * CC;
#pragma unroll
        for (int i = 0; i < 2; ++i) {
            int u = tid + i * 512;
            int r = u >> 4, c0 = (u & 15) * 8;
            *(i32x4*)&Asm[r][c0] = *(const i32x4*)(src + (size_t)(m0 + r) * CC + c0);
        }
    } else {
#pragma unroll
        for (int i = 0; i < 4; ++i) {
            int u = tid + i * 512;
            int r = u >> 5, c4 = (u & 31) * 4;
            float4 a4 = *(const float4*)(io + (size_t)(m0 + r) * CC + c4);
            Asm[r][c4+0] = f2bf(a4.x); Asm[r][c4+1] = f2bf(a4.y);
            Asm[r][c4+2] = f2bf(a4.z); Asm[r][c4+3] = f2bf(a4.w);
        }
    }
    __syncthreads();

    const int wid = tid >> 6, lane = tid & 63, l16 = lane & 15, lh = lane >> 4;
    const int wm = (wid >> 2) * 32;
    const int wn = (wid & 3) * 32;
    f32x4 acc[2][2];
#pragma unroll
    for (int tr = 0; tr < 2; ++tr)
#pragma unroll
        for (int nt = 0; nt < 2; ++nt)
            acc[tr][nt] = (f32x4){0.f, 0.f, 0.f, 0.f};

#pragma unroll
    for (int kk = 0; kk < 4; ++kk) {
        short8 a[2], b[2];
#pragma unroll
        for (int tr = 0; tr < 2; ++tr)
            a[tr] = *(const short8*)&Asm[wm + tr*16 + l16][kk*32 + lh*8];
#pragma unroll
        for (int nt = 0; nt < 2; ++nt)
            b[nt] = *(const short8*)&Wsm[wn + nt*16 + l16][kk*32 + lh*8];
#pragma unroll
        for (int tr = 0; tr < 2; ++tr)
#pragma unroll
            for (int nt = 0; nt < 2; ++nt)
                acc[tr][nt] = mfma16(a[tr], b[nt], acc[tr][nt]);
    }

#pragma unroll
    for (int tr = 0; tr < 2; ++tr)
#pragma unroll
        for (int nt = 0; nt < 2; ++nt) {
            int c = wn + nt*16 + l16;
            float bias = bo[c];
#pragma unroll
            for (int j = 0; j < 4; ++j) {
                int r = m0 + wm + tr*16 + lh*4 + j;
                io[(size_t)r * CC + c] = acc[tr][nt][j] + bias + feat[(size_t)r * CC + c];
            }
        }
}

// ---------------------------------------------------------------------------
extern "C" void kernel_launch(void* const* d_in, const int* in_sizes, int n_in,
                              void* d_out, int out_size, void* d_ws, size_t ws_size,
                              hipStream_t stream)
{
    const float* featL = (const float*)d_in[0];
    const float* featR = (const float*)d_in[1];
    const float* WpL   = (const float*)d_in[2];
    const float* WpR   = (const float*)d_in[3];
    const float* bpL   = (const float*)d_in[4];
    const float* bpR   = (const float*)d_in[5];
    const float* WoL   = (const float*)d_in[6];
    const float* boL   = (const float*)d_in[7];
    const float* WoR   = (const float*)d_in[8];
    const float* boR   = (const float*)d_in[9];
    const float* nw    = (const float*)d_in[10];
    const float* nb    = (const float*)d_in[11];

    float* out = (float*)d_out;
    ushort_t* kvL = (ushort_t*)d_ws;                 // [TOK][256] bf16
    ushort_t* kvR = kvL + (size_t)TOK * 256;         // [TOK][256] bf16
    ushort_t* aout = kvR + (size_t)TOK * 256;        // [2][TOK][128] bf16 (optional)
    ushort_t* Wb  = (ushort_t*)d_out;                // temp bf16 weights; overwritten later

    const size_t need_bf16 = (size_t)TOK * 256 * 2 * 2 + (size_t)TOK * CC * 2 * 2;
    const bool bf16path = ws_size >= need_bf16;

    k_prep<<<dim3(64), 256, 0, stream>>>(WpL, WpR, Wb);
    k_ln_proj<<<dim3(2048, 2), 256, 0, stream>>>(featL, featR, Wb,
                                                 bpL, bpR, nw, nb, kvL, kvR);
    if (bf16path) {
        k_attn<1><<<dim3(4096), 512, 0, stream>>>(kvL, kvR, out, aout);
        k_outproj<1><<<dim3(TOK / 64, 2), 512, 0, stream>>>(out, aout, featL, featR,
                                                            WoL, WoR, boL, boR);
    } else {
        k_attn<0><<<dim3(4096), 512, 0, stream>>>(kvL, kvR, out, aout);
        k_outproj<0><<<dim3(TOK / 64, 2), 512, 0, stream>>>(out, aout, featL, featR,
                                                            WoL, WoR, boL, boR);
    }
}

// Round 6
// 252.918 us; speedup vs baseline: 2.1264x; 1.0422x over previous
//
#include <hip/hip_runtime.h>
#include <hip/hip_bf16.h>

#define BH   512
#define NW   256
#define CC   128
#define TOK  (BH * NW)   // 131072 tokens per side

typedef __attribute__((ext_vector_type(8))) short short8;
typedef __attribute__((ext_vector_type(4))) float f32x4;
typedef __attribute__((ext_vector_type(4))) int   i32x4;
typedef __attribute__((ext_vector_type(4))) unsigned short us4;
typedef __attribute__((ext_vector_type(2))) unsigned int u32x2;
typedef unsigned short ushort_t;

static __device__ __forceinline__ f32x4 mfma16(short8 a, short8 b, f32x4 c) {
    return __builtin_amdgcn_mfma_f32_16x16x32_bf16(a, b, c, 0, 0, 0);
}

// float -> bf16 bits, round-to-nearest-even
static __device__ __forceinline__ ushort_t f2bf(float f) {
    unsigned int u = __float_as_uint(f);
    u = (u + 0x7fffu + ((u >> 16) & 1u)) >> 16;
    return (ushort_t)u;
}
// pack 2 f32 -> 1 u32 of 2 bf16 via the compiler-managed packed convert
static __device__ __forceinline__ unsigned int pk2(float a, float b) {
    __hip_bfloat162 h = __float22bfloat162_rn(make_float2(a, b));
    return *reinterpret_cast<unsigned int*>(&h);
}

// ---------------------------------------------------------------------------
// Kernel 0: convert projection weights f32 -> bf16 into scratch at d_out
// (read by k_ln_proj; d_out later fully rewritten by attn/outproj).
// ---------------------------------------------------------------------------
__global__ __launch_bounds__(256)
void k_prep(const float* __restrict__ WpL, const float* __restrict__ WpR,
            ushort_t* __restrict__ Wb)   // [2][256][128] bf16
{
    int e = (blockIdx.x * 256 + threadIdx.x) * 4;   // 0..65532
    const float* src = (e < 32768) ? (WpL + e) : (WpR + e - 32768);
    float4 v = *(const float4*)src;
    us4 o;
    o[0] = f2bf(v.x); o[1] = f2bf(v.y); o[2] = f2bf(v.z); o[3] = f2bf(v.w);
    *(us4*)(Wb + e) = o;
}

// ---------------------------------------------------------------------------
// Kernel 1: fused LayerNorm + KV projection.
//   kv[token][0..255] = LN(feat[token]) @ Wp^T + bp   (bf16)
//   l_k half (side 0, features<128) pre-scaled by 0.1*log2(e) so attention
//   can use raw exp2 (no max subtraction, no log2e mul).
// ---------------------------------------------------------------------------
__global__ __launch_bounds__(256, 2)
void k_ln_proj(const float* __restrict__ featL, const float* __restrict__ featR,
               const ushort_t* __restrict__ Wb,
               const float* __restrict__ bL,    const float* __restrict__ bR,
               const float* __restrict__ nw,    const float* __restrict__ nb,
               ushort_t* __restrict__ kvL,      ushort_t* __restrict__ kvR)
{
    const int side = blockIdx.y;
    const float* feat = side ? featR : featL;
    const ushort_t* W = Wb + side * 32768;          // [256][128] bf16
    const float* bp   = side ? bR : bL;
    ushort_t*    kv   = side ? kvR : kvL;

    const int m0  = blockIdx.x * 64;
    const int tid = threadIdx.x;
    const int wid = tid >> 6, lane = tid & 63, l16 = lane & 15, lh = lane >> 4;
    const int wn  = wid * 64;                       // wave's feature slice

    __shared__ ushort_t Asm[64][136];
    __shared__ float    nwb[2][128];

    // ---- issue W-fragment + bias loads up-front (resolve under LN) ----
    short8 Bf[16];                                  // [kk][tn]
#pragma unroll
    for (int kk = 0; kk < 4; ++kk)
#pragma unroll
        for (int tn = 0; tn < 4; ++tn)
            Bf[kk*4 + tn] = *(const short8*)(W + (size_t)(wn + tn*16 + l16) * CC + kk*32 + lh*8);
    float4 bias[4];
#pragma unroll
    for (int tn = 0; tn < 4; ++tn)
        bias[tn] = *(const float4*)(bp + wn + tn*16 + lh*4);

    if (tid < 128) { nwb[0][tid] = nw[tid]; nwb[1][tid] = nb[tid]; }
    __syncthreads();

    // ---- LayerNorm: 4 threads/row, 32 elems each, 64 rows ----
    {
        const int row = tid >> 2;
        const int q   = tid & 3;
        const float* fr = feat + (size_t)(m0 + row) * CC + q * 32;
        float x[32];
        float s = 0.f, s2 = 0.f;
#pragma unroll
        for (int i = 0; i < 8; ++i) {
            float4 v = *(const float4*)(fr + i * 4);
            x[i*4+0]=v.x; x[i*4+1]=v.y; x[i*4+2]=v.z; x[i*4+3]=v.w;
            s  += v.x + v.y + v.z + v.w;
            s2 += v.x*v.x + v.y*v.y + v.z*v.z + v.w*v.w;
        }
#pragma unroll
        for (int m = 1; m < 4; m <<= 1) { s += __shfl_xor(s, m); s2 += __shfl_xor(s2, m); }
        float mu   = s * (1.f / 128.f);
        float var  = s2 * (1.f / 128.f) - mu * mu;
        float rstd = rsqrtf(var + 1e-5f);
#pragma unroll
        for (int h = 0; h < 4; ++h) {
            short8 o;
#pragma unroll
            for (int i = 0; i < 8; ++i) {
                int c = q * 32 + h * 8 + i;
                o[i] = (short)f2bf((x[h*8+i] - mu) * rstd * nwb[0][c] + nwb[1][c]);
            }
            *(short8*)&Asm[row][q * 32 + h * 8] = o;
        }
    }
    __syncthreads();

    // ---- MFMA: wave = 64 tokens x 64 features; A from LDS, B from regs ----
    f32x4 acc[4][4];                                // [m-tile][n-frag]
#pragma unroll
    for (int mt = 0; mt < 4; ++mt)
#pragma unroll
        for (int tn = 0; tn < 4; ++tn)
            acc[mt][tn] = (f32x4){0.f, 0.f, 0.f, 0.f};

#pragma unroll
    for (int kk = 0; kk < 4; ++kk) {
        short8 a[4];
#pragma unroll
        for (int mt = 0; mt < 4; ++mt)
            a[mt] = *(const short8*)&Asm[mt*16 + l16][kk*32 + lh*8];
#pragma unroll
        for (int tn = 0; tn < 4; ++tn)
#pragma unroll
            for (int mt = 0; mt < 4; ++mt)
                acc[mt][tn] = mfma16(Bf[kk*4 + tn], a[mt], acc[mt][tn]); // col=token, row=feat
    }

    // 0.1 (attn scale) * log2(e) (exp2 base conversion), folded into l_k
    const float kscale = (side == 0 && wn < 128) ? 0.14426950408889634f : 1.0f;
#pragma unroll
    for (int mt = 0; mt < 4; ++mt)
#pragma unroll
        for (int tn = 0; tn < 4; ++tn) {
            const int f0 = wn + tn*16 + lh*4;
            const int token = m0 + mt*16 + l16;
            const float bb[4] = {bias[tn].x, bias[tn].y, bias[tn].z, bias[tn].w};
            us4 o;
#pragma unroll
            for (int j = 0; j < 4; ++j)
                o[j] = f2bf((acc[mt][tn][j] + bb[j]) * kscale);
            *(us4*)(kv + (size_t)token * 256 + f0) = o;
        }
}

// ---------------------------------------------------------------------------
// Kernel 2: attention, one (n, head, dir) per block; 8 waves x 32-row stripes.
//   Scores are bounded (|S|<~3.2 in exp2 domain after folded 0.1*log2e scale
//   of LN'd/Xavier projections), so softmax runs WITHOUT max-tracking:
//   p = exp2(s), normalize once at the end.
//   kB and pL use 64B rows + XOR slot swizzle (col ^= 8*(row&3)) -> b128
//   reads land 2 lanes/slot (free); LDS = 49.5 KB.
// ---------------------------------------------------------------------------
template<int BF16OUT>
__global__ __launch_bounds__(512, 4)
void k_attn(const ushort_t* __restrict__ kvL, const ushort_t* __restrict__ kvR,
            float* __restrict__ outFBase, ushort_t* __restrict__ outBBase)
{
    const int bx   = blockIdx.x;
    const int work = (bx & 7) * 512 + (bx >> 3);    // 4096 = 8 chunks x 512
    const int n    = work >> 3;
    const int e    = (work >> 1) & 3;
    const int dir  = work & 1;
    const ushort_t* kvA = dir ? kvR : kvL;
    const ushort_t* kvB = dir ? kvL : kvR;

    const int tid = threadIdx.x;
    const int wid = tid >> 6, lane = tid & 63, l16 = lane & 15, lh = lane >> 4;
    const int W0 = wid * 32;
    const int q  = l16 & 3;                         // XOR-swizzle row class

    __shared__ ushort_t kB[256][32];     // keys of B side, swizzled 64B rows
    __shared__ ushort_t vT[32][274];     // V transposed [c][v]
    __shared__ ushort_t pL[8][32][32];   // wave-private P chunk, swizzled

    // ---- stage kB (swizzled: 16B slot ^= row&3) ----
    {
        const ushort_t* src = kvB + (size_t)n * 256 * 256 + e * 32;
#pragma unroll
        for (int p = 0; p < 2; ++p) {
            int u = tid + p * 512;
            int r = u >> 2, slot = u & 3;
            *(i32x4*)&kB[r][(slot ^ (r & 3)) * 8] =
                *(const i32x4*)(src + (size_t)r * 256 + slot * 8);
        }
    }
    // ---- stage vT (transpose via u32 repack) ----
    {
        const ushort_t* src = kvB + (size_t)n * 256 * 256 + 128 + e * 32;
#pragma unroll
        for (int u4 = 0; u4 < 4; ++u4) {
            int unit = tid + u4 * 512;              // 2048 = 16 c-pairs x 128 v-pairs
            int cp = unit & 15, vp = unit >> 4;
            unsigned int w0 = *(const unsigned int*)(src + (size_t)(vp*2    ) * 256 + cp*2);
            unsigned int w1 = *(const unsigned int*)(src + (size_t)(vp*2 + 1) * 256 + cp*2);
            *(unsigned int*)&vT[cp*2    ][vp*2] = (w0 & 0xffffu) | (w1 << 16);
            *(unsigned int*)&vT[cp*2 + 1][vp*2] = (w0 >> 16) | (w1 & 0xffff0000u);
        }
    }
    // ---- kA fragments direct from global ----
    short8 aK[2];
#pragma unroll
    for (int tr = 0; tr < 2; ++tr)
        aK[tr] = *(const short8*)(kvA + (size_t)(n*256 + W0 + tr*16 + l16) * 256 + e*32 + lh*8);

    __syncthreads();

    f32x4 oacc[2][2];
#pragma unroll
    for (int tr = 0; tr < 2; ++tr)
#pragma unroll
        for (int ct = 0; ct < 2; ++ct)
            oacc[tr][ct] = (f32x4){0.f, 0.f, 0.f, 0.f};
    float lrun[2] = {0.f, 0.f};

#pragma unroll 2
    for (int nc = 0; nc < 8; ++nc) {
        const int vc0 = nc * 32;

        // ---- QK chunk: S[w, vc0..vc0+31] (swizzled kB read) ----
        short8 bk0 = *(const short8*)&kB[vc0      + l16][8 * (lh ^ q)];
        short8 bk1 = *(const short8*)&kB[vc0 + 16 + l16][8 * (lh ^ q)];
        f32x4 s[2][2];
#pragma unroll
        for (int tr = 0; tr < 2; ++tr) {
            s[tr][0] = mfma16(bk0, aK[tr], (f32x4){0.f,0.f,0.f,0.f});
            s[tr][1] = mfma16(bk1, aK[tr], (f32x4){0.f,0.f,0.f,0.f});
        }

        // ---- p = exp2(s); lane-local partial sums; pack -> pL (swizzled) ----
#pragma unroll
        for (int tr = 0; tr < 2; ++tr) {
#pragma unroll
            for (int tc = 0; tc < 2; ++tc) {
                float p0 = exp2f(s[tr][tc][0]);
                float p1 = exp2f(s[tr][tc][1]);
                float p2 = exp2f(s[tr][tc][2]);
                float p3 = exp2f(s[tr][tc][3]);
                lrun[tr] += (p0 + p1) + (p2 + p3);
                u32x2 w;
                w[0] = pk2(p0, p1);
                w[1] = pk2(p2, p3);
                *(u32x2*)&pL[wid][tr*16 + l16][(16*tc + 4*lh) ^ (8*q)] = w;
            }
        }

        // ---- PV for this 32-wide k-slice ----
        short8 aP[2], bV[2];
#pragma unroll
        for (int tr = 0; tr < 2; ++tr)
            aP[tr] = *(const short8*)&pL[wid][tr*16 + l16][8 * (lh ^ q)];
#pragma unroll
        for (int ct = 0; ct < 2; ++ct)
            bV[ct] = *(const short8*)&vT[ct*16 + l16][vc0 + lh*8];
#pragma unroll
        for (int tr = 0; tr < 2; ++tr)
#pragma unroll
            for (int ct = 0; ct < 2; ++ct)
                oacc[tr][ct] = mfma16(bV[ct], aP[tr], oacc[tr][ct]); // col=w, row=c
    }

    // ---- one cross-lane sum reduction at the end, then normalize + store ----
#pragma unroll
    for (int tr = 0; tr < 2; ++tr) {
        float sum = lrun[tr];
        sum += __shfl_xor(sum, 16);
        sum += __shfl_xor(sum, 32);
        float rinv = 1.f / sum;
        const int token = n * 256 + W0 + tr*16 + l16;
        if (BF16OUT) {
            ushort_t* outB = outBBase + (size_t)dir * TOK * CC;
#pragma unroll
            for (int ct = 0; ct < 2; ++ct) {
                us4 o;
#pragma unroll
                for (int j = 0; j < 4; ++j)
                    o[j] = f2bf(oacc[tr][ct][j] * rinv);
                *(us4*)(outB + (size_t)token * CC + e*32 + ct*16 + lh*4) = o;
            }
        } else {
            float* outF = outFBase + (size_t)dir * TOK * CC;
#pragma unroll
            for (int ct = 0; ct < 2; ++ct) {
                float4 o;
                o.x = oacc[tr][ct][0] * rinv;
                o.y = oacc[tr][ct][1] * rinv;
                o.z = oacc[tr][ct][2] * rinv;
                o.w = oacc[tr][ct][3] * rinv;
                *(float4*)(outF + (size_t)token * CC + e*32 + ct*16 + lh*4) = o;
            }
        }
    }
}

// ---------------------------------------------------------------------------
// Kernel 3: out projection + bias + residual -> d_out (f32).
// ---------------------------------------------------------------------------
template<int BF16IN>
__global__ __launch_bounds__(512, 4)
void k_outproj(float* __restrict__ outBase, const ushort_t* __restrict__ aoutBase,
               const float* __restrict__ featL, const float* __restrict__ featR,
               const float* __restrict__ WoL,   const float* __restrict__ WoR,
               const float* __restrict__ boL,   const float* __restrict__ boR)
{
    const int side = blockIdx.y;
    float* io = outBase + (size_t)side * TOK * CC;
    const float* feat = side ? featR : featL;
    const float* Wo   = side ? WoR   : WoL;
    const float* bo   = side ? boR   : boL;

    const int m0 = blockIdx.x * 64;
    const int tid = threadIdx.x;

    __shared__ ushort_t Asm[64][136];
    __shared__ ushort_t Wsm[128][136];

#pragma unroll
    for (int i = 0; i < 8; ++i) {
        int u = tid + i * 512;
        int r = u >> 5, c4 = (u & 31) * 4;
        float4 w4 = *(const float4*)(Wo + (size_t)r * CC + c4);
        Wsm[r][c4+0] = f2bf(w4.x); Wsm[r][c4+1] = f2bf(w4.y);
        Wsm[r][c4+2] = f2bf(w4.z); Wsm[r][c4+3] = f2bf(w4.w);
    }
    if (BF16IN) {
        const ushort_t* src = aoutBase + (size_t)side * TOK * CC;
#pragma unroll
        for (int i = 0; i < 2; ++i) {
            int u = tid + i * 512;
            int r = u >> 4, c0 = (u & 15) * 8;
            *(i32x4*)&Asm[r][c0] = *(const i32x4*)(src + (size_t)(m0 + r) * CC + c0);
        }
    } else {
#pragma unroll
        for (int i = 0; i < 4; ++i) {
            int u = tid + i * 512;
            int r = u >> 5, c4 = (u & 31) * 4;
            float4 a4 = *(const float4*)(io + (size_t)(m0 + r) * CC + c4);
            Asm[r][c4+0] = f2bf(a4.x); Asm[r][c4+1] = f2bf(a4.y);
            Asm[r][c4+2] = f2bf(a4.z); Asm[r][c4+3] = f2bf(a4.w);
        }
    }
    __syncthreads();

    const int wid = tid >> 6, lane = tid & 63, l16 = lane & 15, lh = lane >> 4;
    const int wm = (wid >> 2) * 32;
    const int wn = (wid & 3) * 32;
    f32x4 acc[2][2];
#pragma unroll
    for (int tr = 0; tr < 2; ++tr)
#pragma unroll
        for (int nt = 0; nt < 2; ++nt)
            acc[tr][nt] = (f32x4){0.f, 0.f, 0.f, 0.f};

#pragma unroll
    for (int kk = 0; kk < 4; ++kk) {
        short8 a[2], b[2];
#pragma unroll
        for (int tr = 0; tr < 2; ++tr)
            a[tr] = *(const short8*)&Asm[wm + tr*16 + l16][kk*32 + lh*8];
#pragma unroll
        for (int nt = 0; nt < 2; ++nt)
            b[nt] = *(const short8*)&Wsm[wn + nt*16 + l16][kk*32 + lh*8];
#pragma unroll
        for (int tr = 0; tr < 2; ++tr)
#pragma unroll
            for (int nt = 0; nt < 2; ++nt)
                acc[tr][nt] = mfma16(a[tr], b[nt], acc[tr][nt]);
    }

#pragma unroll
    for (int tr = 0; tr < 2; ++tr)
#pragma unroll
        for (int nt = 0; nt < 2; ++nt) {
            int c = wn + nt*16 + l16;
            float bias = bo[c];
#pragma unroll
            for (int j = 0; j < 4; ++j) {
                int r = m0 + wm + tr*16 + lh*4 + j;
                io[(size_t)r * CC + c] = acc[tr][nt][j] + bias + feat[(size_t)r * CC + c];
            }
        }
}

// ---------------------------------------------------------------------------
extern "C" void kernel_launch(void* const* d_in, const int* in_sizes, int n_in,
                              void* d_out, int out_size, void* d_ws, size_t ws_size,
                              hipStream_t stream)
{
    const float* featL = (const float*)d_in[0];
    const float* featR = (const float*)d_in[1];
    const float* WpL   = (const float*)d_in[2];
    const float* WpR   = (const float*)d_in[3];
    const float* bpL   = (const float*)d_in[4];
    const float* bpR   = (const float*)d_in[5];
    const float* WoL   = (const float*)d_in[6];
    const float* boL   = (const float*)d_in[7];
    const float* WoR   = (const float*)d_in[8];
    const float* boR   = (const float*)d_in[9];
    const float* nw    = (const float*)d_in[10];
    const float* nb    = (const float*)d_in[11];

    float* out = (float*)d_out;
    ushort_t* kvL = (ushort_t*)d_ws;                 // [TOK][256] bf16
    ushort_t* kvR = kvL + (size_t)TOK * 256;         // [TOK][256] bf16
    ushort_t* aout = kvR + (size_t)TOK * 256;        // [2][TOK][128] bf16 (optional)
    ushort_t* Wb  = (ushort_t*)d_out;                // temp bf16 weights; overwritten later

    const size_t need_bf16 = (size_t)TOK * 256 * 2 * 2 + (size_t)TOK * CC * 2 * 2;
    const bool bf16path = ws_size >= need_bf16;

    k_prep<<<dim3(64), 256, 0, stream>>>(WpL, WpR, Wb);
    k_ln_proj<<<dim3(2048, 2), 256, 0, stream>>>(featL, featR, Wb,
                                                 bpL, bpR, nw, nb, kvL, kvR);
    if (bf16path) {
        k_attn<1><<<dim3(4096), 512, 0, stream>>>(kvL, kvR, out, aout);
        k_outproj<1><<<dim3(TOK / 64, 2), 512, 0, stream>>>(out, aout, featL, featR,
                                                            WoL, WoR, boL, boR);
    } else {
        k_attn<0><<<dim3(4096), 512, 0, stream>>>(kvL, kvR, out, aout);
        k_outproj<0><<<dim3(TOK / 64, 2), 512, 0, stream>>>(out, aout, featL, featR,
                                                            WoL, WoR, boL, boR);
    }
}

// Round 7
// 241.462 us; speedup vs baseline: 2.2273x; 1.0474x over previous
//
#include <hip/hip_runtime.h>
#include <hip/hip_bf16.h>

#define BH   512
#define NW   256
#define CC   128
#define TOK  (BH * NW)   // 131072 tokens per side

typedef __attribute__((ext_vector_type(8))) short short8;
typedef __attribute__((ext_vector_type(4))) float f32x4;
typedef __attribute__((ext_vector_type(4))) int   i32x4;
typedef __attribute__((ext_vector_type(4))) unsigned short us4;
typedef __attribute__((ext_vector_type(2))) unsigned int u32x2;
typedef unsigned short ushort_t;

static __device__ __forceinline__ f32x4 mfma16(short8 a, short8 b, f32x4 c) {
    return __builtin_amdgcn_mfma_f32_16x16x32_bf16(a, b, c, 0, 0, 0);
}

// pack 2 f32 -> 1 u32 of 2 bf16 (compiler-managed packed convert, RNE)
static __device__ __forceinline__ unsigned int pk2(float a, float b) {
    __hip_bfloat162 h = __float22bfloat162_rn(make_float2(a, b));
    return *reinterpret_cast<unsigned int*>(&h);
}
static __device__ __forceinline__ ushort_t f2bf(float f) {
    unsigned int u = __float_as_uint(f);
    u = (u + 0x7fffu + ((u >> 16) & 1u)) >> 16;
    return (ushort_t)u;
}

// ---------------------------------------------------------------------------
// Kernel 0: fold LayerNorm affine into projection weights.
//   W'[o][c] = W[o][c] * gamma[c]  (bf16)
//   bias'[o] = bp[o] + sum_c beta[c] * W[o][c]   (f32)
// Stored at the start of d_out (consumed by k_ln_proj, later overwritten).
// grid(8), 256 thr: 4 threads per output row, 32 cols each.
// ---------------------------------------------------------------------------
__global__ __launch_bounds__(256)
void k_prep(const float* __restrict__ WpL, const float* __restrict__ WpR,
            const float* __restrict__ bpL, const float* __restrict__ bpR,
            const float* __restrict__ nw,  const float* __restrict__ nb,
            ushort_t* __restrict__ Wb, float* __restrict__ bias2)
{
    const int gid = blockIdx.x * 256 + threadIdx.x;  // 0..2047
    const int row = gid >> 2;                        // 0..511 = side*256 + o
    const int q   = gid & 3;
    const int side = row >> 8;
    const int o    = row & 255;
    const float* Wp = side ? WpR : WpL;
    const float* bp = side ? bpR : bpL;
    const float* wr = Wp + (size_t)o * 128 + q * 32;

    float acc = 0.f;
#pragma unroll
    for (int g = 0; g < 4; ++g) {
        const int c = q * 32 + g * 8;
        float4 wa = *(const float4*)(wr + g * 8);
        float4 wb = *(const float4*)(wr + g * 8 + 4);
        float4 ga = *(const float4*)(nw + c);
        float4 gb = *(const float4*)(nw + c + 4);
        float4 ba = *(const float4*)(nb + c);
        float4 bb = *(const float4*)(nb + c + 4);
        acc += wa.x*ba.x + wa.y*ba.y + wa.z*ba.z + wa.w*ba.w
             + wb.x*bb.x + wb.y*bb.y + wb.z*bb.z + wb.w*bb.w;
        u32x2 o0, o1;
        o0[0] = pk2(wa.x*ga.x, wa.y*ga.y);
        o0[1] = pk2(wa.z*ga.z, wa.w*ga.w);
        o1[0] = pk2(wb.x*gb.x, wb.y*gb.y);
        o1[1] = pk2(wb.z*gb.z, wb.w*gb.w);
        *(u32x2*)(Wb + (size_t)row * 128 + c)     = o0;
        *(u32x2*)(Wb + (size_t)row * 128 + c + 4) = o1;
    }
    acc += __shfl_xor(acc, 1);
    acc += __shfl_xor(acc, 2);
    if (q == 0) bias2[row] = bp[o] + acc;
}

// ---------------------------------------------------------------------------
// Kernel 1: fused LayerNorm + KV projection (affine pre-folded into W').
//   kv[token][0..255] = z(token) @ W'^T + bias'  (bf16), z = (x-mu)*rstd
//   l_k half (side 0, features<128) pre-scaled by 0.1*log2(e).
//   grid (2048 m-tiles of 64 tokens, 2 sides), 256 thr.
//   feat loads issued FIRST (HBM long pole); W frags resolve under LN.
//   Epilogue staged through padded LDS -> fully coalesced global stores.
// ---------------------------------------------------------------------------
__global__ __launch_bounds__(256)
void k_ln_proj(const float* __restrict__ featL, const float* __restrict__ featR,
               const ushort_t* __restrict__ Wb, const float* __restrict__ bias2,
               ushort_t* __restrict__ kvL,      ushort_t* __restrict__ kvR)
{
    const int side = blockIdx.y;
    const float* feat = side ? featR : featL;
    const ushort_t* W = Wb + side * 32768;          // [256][128] bf16
    const float* b2   = bias2 + side * 256;
    ushort_t*    kv   = side ? kvR : kvL;

    const int m0  = blockIdx.x * 64;
    const int tid = threadIdx.x;
    const int wid = tid >> 6, lane = tid & 63, l16 = lane & 15, lh = lane >> 4;
    const int wn  = wid * 64;                       // wave's feature slice

    __shared__ ushort_t smem[64 * 260];             // union: Asm then kvS
    ushort_t (*Asm)[136] = (ushort_t (*)[136])smem; // LN'd activations
    ushort_t (*kvS)[260] = (ushort_t (*)[260])smem; // staged output (pad 4)

    // ---- phase 0: feat loads first ----
    const int row = tid >> 2, q = tid & 3;
    const float* fr = feat + (size_t)(m0 + row) * CC + q * 32;
    float x[32];
#pragma unroll
    for (int i = 0; i < 8; ++i) {
        float4 v = *(const float4*)(fr + i * 4);
        x[i*4+0]=v.x; x[i*4+1]=v.y; x[i*4+2]=v.z; x[i*4+3]=v.w;
    }

    // ---- W-fragment + bias loads (resolve under LN compute) ----
    short8 Bf[16];                                  // [kk][tn]
#pragma unroll
    for (int kk = 0; kk < 4; ++kk)
#pragma unroll
        for (int tn = 0; tn < 4; ++tn)
            Bf[kk*4 + tn] = *(const short8*)(W + (size_t)(wn + tn*16 + l16) * CC + kk*32 + lh*8);
    float4 bias[4];
#pragma unroll
    for (int tn = 0; tn < 4; ++tn)
        bias[tn] = *(const float4*)(b2 + wn + tn*16 + lh*4);

    // ---- LayerNorm (no affine): z = (x-mu)*rstd ----
    {
        float s = 0.f, s2 = 0.f;
#pragma unroll
        for (int i = 0; i < 32; ++i) { s += x[i]; s2 += x[i]*x[i]; }
#pragma unroll
        for (int m = 1; m < 4; m <<= 1) { s += __shfl_xor(s, m); s2 += __shfl_xor(s2, m); }
        float mu   = s * (1.f / 128.f);
        float var  = s2 * (1.f / 128.f) - mu * mu;
        float rstd = rsqrtf(var + 1e-5f);
        float a = rstd, bsh = -mu * rstd;
#pragma unroll
        for (int g = 0; g < 4; ++g) {
            i32x4 o;
#pragma unroll
            for (int k = 0; k < 4; ++k)
                o[k] = (int)pk2(x[g*8 + 2*k] * a + bsh, x[g*8 + 2*k + 1] * a + bsh);
            *(i32x4*)&Asm[row][q * 32 + g * 8] = o;
        }
    }
    __syncthreads();

    // ---- MFMA: wave = 64 tokens x 64 features; A from LDS, B from regs ----
    f32x4 acc[4][4];                                // [m-tile][n-frag]
#pragma unroll
    for (int mt = 0; mt < 4; ++mt)
#pragma unroll
        for (int tn = 0; tn < 4; ++tn)
            acc[mt][tn] = (f32x4){0.f, 0.f, 0.f, 0.f};

#pragma unroll
    for (int kk = 0; kk < 4; ++kk) {
        short8 a[4];
#pragma unroll
        for (int mt = 0; mt < 4; ++mt)
            a[mt] = *(const short8*)&Asm[mt*16 + l16][kk*32 + lh*8];
#pragma unroll
        for (int tn = 0; tn < 4; ++tn)
#pragma unroll
            for (int mt = 0; mt < 4; ++mt)
                acc[mt][tn] = mfma16(Bf[kk*4 + tn], a[mt], acc[mt][tn]); // col=token, row=feat
    }
    __syncthreads();   // all Asm reads done before kvS overwrites

    // ---- epilogue: bias + scale -> bf16 -> staged LDS ----
    const float kscale = (side == 0 && wn < 128) ? 0.14426950408889634f : 1.0f;
#pragma unroll
    for (int mt = 0; mt < 4; ++mt)
#pragma unroll
        for (int tn = 0; tn < 4; ++tn) {
            const int r    = mt*16 + l16;                 // token-local
            const int slot = (wn >> 2) + tn*4 + lh;       // 8B slot (feature/4)
            float v0 = (acc[mt][tn][0] + bias[tn].x) * kscale;
            float v1 = (acc[mt][tn][1] + bias[tn].y) * kscale;
            float v2 = (acc[mt][tn][2] + bias[tn].z) * kscale;
            float v3 = (acc[mt][tn][3] + bias[tn].w) * kscale;
            u32x2 wv;
            wv[0] = pk2(v0, v1);
            wv[1] = pk2(v2, v3);
            *(u32x2*)&kvS[r][slot * 4] = wv;
        }
    __syncthreads();

    // ---- coalesced copy-out: per wave 512B contiguous per iteration ----
#pragma unroll
    for (int it = 0; it < 16; ++it) {
        int u = it * 256 + tid;
        int r = u >> 6, sl = u & 63;
        u32x2 wv = *(const u32x2*)&kvS[r][sl * 4];
        *(u32x2*)(kv + (size_t)(m0 + r) * 256 + sl * 4) = wv;
    }
}

// ---------------------------------------------------------------------------
// Kernel 2: attention, one (n, head, dir) per block; 8 waves x 32-row stripes.
//   No-max softmax (|S| bounded): p = exp2(s), normalize once at the end.
//   kB and pL use 64B rows + XOR slot swizzle; single barrier.
// ---------------------------------------------------------------------------
template<int BF16OUT>
__global__ __launch_bounds__(512, 4)
void k_attn(const ushort_t* __restrict__ kvL, const ushort_t* __restrict__ kvR,
            float* __restrict__ outFBase, ushort_t* __restrict__ outBBase)
{
    const int bx   = blockIdx.x;
    const int work = (bx & 7) * 512 + (bx >> 3);    // 4096 = 8 chunks x 512
    const int n    = work >> 3;
    const int e    = (work >> 1) & 3;
    const int dir  = work & 1;
    const ushort_t* kvA = dir ? kvR : kvL;
    const ushort_t* kvB = dir ? kvL : kvR;

    const int tid = threadIdx.x;
    const int wid = tid >> 6, lane = tid & 63, l16 = lane & 15, lh = lane >> 4;
    const int W0 = wid * 32;
    const int q  = l16 & 3;                         // XOR-swizzle row class

    __shared__ ushort_t kB[256][32];     // keys of B side, swizzled 64B rows
    __shared__ ushort_t vT[32][274];     // V transposed [c][v]
    __shared__ ushort_t pL[8][32][32];   // wave-private P chunk, swizzled

    // ---- stage kB (swizzled: 16B slot ^= row&3) ----
    {
        const ushort_t* src = kvB + (size_t)n * 256 * 256 + e * 32;
#pragma unroll
        for (int p = 0; p < 2; ++p) {
            int u = tid + p * 512;
            int r = u >> 2, slot = u & 3;
            *(i32x4*)&kB[r][(slot ^ (r & 3)) * 8] =
                *(const i32x4*)(src + (size_t)r * 256 + slot * 8);
        }
    }
    // ---- stage vT (transpose via u32 repack) ----
    {
        const ushort_t* src = kvB + (size_t)n * 256 * 256 + 128 + e * 32;
#pragma unroll
        for (int u4 = 0; u4 < 4; ++u4) {
            int unit = tid + u4 * 512;              // 2048 = 16 c-pairs x 128 v-pairs
            int cp = unit & 15, vp = unit >> 4;
            unsigned int w0 = *(const unsigned int*)(src + (size_t)(vp*2    ) * 256 + cp*2);
            unsigned int w1 = *(const unsigned int*)(src + (size_t)(vp*2 + 1) * 256 + cp*2);
            *(unsigned int*)&vT[cp*2    ][vp*2] = (w0 & 0xffffu) | (w1 << 16);
            *(unsigned int*)&vT[cp*2 + 1][vp*2] = (w0 >> 16) | (w1 & 0xffff0000u);
        }
    }
    // ---- kA fragments direct from global ----
    short8 aK[2];
#pragma unroll
    for (int tr = 0; tr < 2; ++tr)
        aK[tr] = *(const short8*)(kvA + (size_t)(n*256 + W0 + tr*16 + l16) * 256 + e*32 + lh*8);

    __syncthreads();

    f32x4 oacc[2][2];
#pragma unroll
    for (int tr = 0; tr < 2; ++tr)
#pragma unroll
        for (int ct = 0; ct < 2; ++ct)
            oacc[tr][ct] = (f32x4){0.f, 0.f, 0.f, 0.f};
    float lrun[2] = {0.f, 0.f};

#pragma unroll 2
    for (int nc = 0; nc < 8; ++nc) {
        const int vc0 = nc * 32;

        // ---- QK chunk: S[w, vc0..vc0+31] (swizzled kB read) ----
        short8 bk0 = *(const short8*)&kB[vc0      + l16][8 * (lh ^ q)];
        short8 bk1 = *(const short8*)&kB[vc0 + 16 + l16][8 * (lh ^ q)];
        f32x4 s[2][2];
#pragma unroll
        for (int tr = 0; tr < 2; ++tr) {
            s[tr][0] = mfma16(bk0, aK[tr], (f32x4){0.f,0.f,0.f,0.f});
            s[tr][1] = mfma16(bk1, aK[tr], (f32x4){0.f,0.f,0.f,0.f});
        }

        // ---- p = exp2(s); lane-local partial sums; pack -> pL (swizzled) ----
#pragma unroll
        for (int tr = 0; tr < 2; ++tr) {
#pragma unroll
            for (int tc = 0; tc < 2; ++tc) {
                float p0 = exp2f(s[tr][tc][0]);
                float p1 = exp2f(s[tr][tc][1]);
                float p2 = exp2f(s[tr][tc][2]);
                float p3 = exp2f(s[tr][tc][3]);
                lrun[tr] += (p0 + p1) + (p2 + p3);
                u32x2 w;
                w[0] = pk2(p0, p1);
                w[1] = pk2(p2, p3);
                *(u32x2*)&pL[wid][tr*16 + l16][(16*tc + 4*lh) ^ (8*q)] = w;
            }
        }

        // ---- PV for this 32-wide k-slice ----
        short8 aP[2], bV[2];
#pragma unroll
        for (int tr = 0; tr < 2; ++tr)
            aP[tr] = *(const short8*)&pL[wid][tr*16 + l16][8 * (lh ^ q)];
#pragma unroll
        for (int ct = 0; ct < 2; ++ct)
            bV[ct] = *(const short8*)&vT[ct*16 + l16][vc0 + lh*8];
#pragma unroll
        for (int tr = 0; tr < 2; ++tr)
#pragma unroll
            for (int ct = 0; ct < 2; ++ct)
                oacc[tr][ct] = mfma16(bV[ct], aP[tr], oacc[tr][ct]); // col=w, row=c
    }

    // ---- one cross-lane sum reduction, then normalize + store ----
#pragma unroll
    for (int tr = 0; tr < 2; ++tr) {
        float sum = lrun[tr];
        sum += __shfl_xor(sum, 16);
        sum += __shfl_xor(sum, 32);
        float rinv = 1.f / sum;
        const int token = n * 256 + W0 + tr*16 + l16;
        if (BF16OUT) {
            ushort_t* outB = outBBase + (size_t)dir * TOK * CC;
#pragma unroll
            for (int ct = 0; ct < 2; ++ct) {
                us4 o;
#pragma unroll
                for (int j = 0; j < 4; ++j)
                    o[j] = f2bf(oacc[tr][ct][j] * rinv);
                *(us4*)(outB + (size_t)token * CC + e*32 + ct*16 + lh*4) = o;
            }
        } else {
            float* outF = outFBase + (size_t)dir * TOK * CC;
#pragma unroll
            for (int ct = 0; ct < 2; ++ct) {
                float4 o;
                o.x = oacc[tr][ct][0] * rinv;
                o.y = oacc[tr][ct][1] * rinv;
                o.z = oacc[tr][ct][2] * rinv;
                o.w = oacc[tr][ct][3] * rinv;
                *(float4*)(outF + (size_t)token * CC + e*32 + ct*16 + lh*4) = o;
            }
        }
    }
}

// ---------------------------------------------------------------------------
// Kernel 3: out projection + bias + residual -> d_out (f32).
// ---------------------------------------------------------------------------
template<int BF16IN>
__global__ __launch_bounds__(512, 4)
void k_outproj(float* __restrict__ outBase, const ushort_t* __restrict__ aoutBase,
               const float* __restrict__ featL, const float* __restrict__ featR,
               const float* __restrict__ WoL,   const float* __restrict__ WoR,
               const float* __restrict__ boL,   const float* __restrict__ boR)
{
    const int side = blockIdx.y;
    float* io = outBase + (size_t)side * TOK * CC;
    const float* feat = side ? featR : featL;
    const float* Wo   = side ? WoR   : WoL;
    const float* bo   = side ? boR   : boL;

    const int m0 = blockIdx.x * 64;
    const int tid = threadIdx.x;

    __shared__ ushort_t Asm[64][136];
    __shared__ ushort_t Wsm[128][136];

#pragma unroll
    for (int i = 0; i < 8; ++i) {
        int u = tid + i * 512;
        int r = u >> 5, c4 = (u & 31) * 4;
        float4 w4 = *(const float4*)(Wo + (size_t)r * CC + c4);
        Wsm[r][c4+0] = f2bf(w4.x); Wsm[r][c4+1] = f2bf(w4.y);
        Wsm[r][c4+2] = f2bf(w4.z); Wsm[r][c4+3] = f2bf(w4.w);
    }
    if (BF16IN) {
        const ushort_t* src = aoutBase + (size_t)side * TOK * CC;
#pragma unroll
        for (int i = 0; i < 2; ++i) {
            int u = tid + i * 512;
            int r = u >> 4, c0 = (u & 15) * 8;
            *(i32x4*)&Asm[r][c0] = *(const i32x4*)(src + (size_t)(m0 + r) * CC + c0);
        }
    } else {
#pragma unroll
        for (int i = 0; i < 4; ++i) {
            int u = tid + i * 512;
            int r = u >> 5, c4 = (u & 31) * 4;
            float4 a4 = *(const float4*)(io + (size_t)(m0 + r) * CC + c4);
            Asm[r][c4+0] = f2bf(a4.x); Asm[r][c4+1] = f2bf(a4.y);
            Asm[r][c4+2] = f2bf(a4.z); Asm[r][c4+3] = f2bf(a4.w);
        }
    }
    __syncthreads();

    const int wid = tid >> 6, lane = tid & 63, l16 = lane & 15, lh = lane >> 4;
    const int wm = (wid >> 2) * 32;
    const int wn = (wid & 3) * 32;
    f32x4 acc[2][2];
#pragma unroll
    for (int tr = 0; tr < 2; ++tr)
#pragma unroll
        for (int nt = 0; nt < 2; ++nt)
            acc[tr][nt] = (f32x4){0.f, 0.f, 0.f, 0.f};

#pragma unroll
    for (int kk = 0; kk < 4; ++kk) {
        short8 a[2], b[2];
#pragma unroll
        for (int tr = 0; tr < 2; ++tr)
            a[tr] = *(const short8*)&Asm[wm + tr*16 + l16][kk*32 + lh*8];
#pragma unroll
        for (int nt = 0; nt < 2; ++nt)
            b[nt] = *(const short8*)&Wsm[wn + nt*16 + l16][kk*32 + lh*8];
#pragma unroll
        for (int tr = 0; tr < 2; ++tr)
#pragma unroll
            for (int nt = 0; nt < 2; ++nt)
                acc[tr][nt] = mfma16(a[tr], b[nt], acc[tr][nt]);
    }

#pragma unroll
    for (int tr = 0; tr < 2; ++tr)
#pragma unroll
        for (int nt = 0; nt < 2; ++nt) {
            int c = wn + nt*16 + l16;
            float bias = bo[c];
#pragma unroll
            for (int j = 0; j < 4; ++j) {
                int r = m0 + wm + tr*16 + lh*4 + j;
                io[(size_t)r * CC + c] = acc[tr][nt][j] + bias + feat[(size_t)r * CC + c];
            }
        }
}

// ---------------------------------------------------------------------------
extern "C" void kernel_launch(void* const* d_in, const int* in_sizes, int n_in,
                              void* d_out, int out_size, void* d_ws, size_t ws_size,
                              hipStream_t stream)
{
    const float* featL = (const float*)d_in[0];
    const float* featR = (const float*)d_in[1];
    const float* WpL   = (const float*)d_in[2];
    const float* WpR   = (const float*)d_in[3];
    const float* bpL   = (const float*)d_in[4];
    const float* bpR   = (const float*)d_in[5];
    const float* WoL   = (const float*)d_in[6];
    const float* boL   = (const float*)d_in[7];
    const float* WoR   = (const float*)d_in[8];
    const float* boR   = (const float*)d_in[9];
    const float* nw    = (const float*)d_in[10];
    const float* nb    = (const float*)d_in[11];

    float* out = (float*)d_out;
    ushort_t* kvL = (ushort_t*)d_ws;                 // [TOK][256] bf16
    ushort_t* kvR = kvL + (size_t)TOK * 256;         // [TOK][256] bf16
    ushort_t* aout = kvR + (size_t)TOK * 256;        // [2][TOK][128] bf16 (optional)
    ushort_t* Wb  = (ushort_t*)d_out;                // W' bf16 [2][256][128]
    float* bias2  = (float*)d_out + 32768;           // bias' f32 [2][256]

    const size_t need_bf16 = (size_t)TOK * 256 * 2 * 2 + (size_t)TOK * CC * 2 * 2;
    const bool bf16path = ws_size >= need_bf16;

    k_prep<<<dim3(8), 256, 0, stream>>>(WpL, WpR, bpL, bpR, nw, nb, Wb, bias2);
    k_ln_proj<<<dim3(2048, 2), 256, 0, stream>>>(featL, featR, Wb, bias2, kvL, kvR);
    if (bf16path) {
        k_attn<1><<<dim3(4096), 512, 0, stream>>>(kvL, kvR, out, aout);
        k_outproj<1><<<dim3(TOK / 64, 2), 512, 0, stream>>>(out, aout, featL, featR,
                                                            WoL, WoR, boL, boR);
    } else {
        k_attn<0><<<dim3(4096), 512, 0, stream>>>(kvL, kvR, out, aout);
        k_outproj<0><<<dim3(TOK / 64, 2), 512, 0, stream>>>(out, aout, featL, featR,
                                                            WoL, WoR, boL, boR);
    }
}

// Round 8
// 214.230 us; speedup vs baseline: 2.5104x; 1.1271x over previous
//
#include <hip/hip_runtime.h>
#include <hip/hip_bf16.h>

#define BH   512
#define NW   256
#define CC   128
#define TOK  (BH * NW)   // 131072 tokens per side

typedef __attribute__((ext_vector_type(8))) short short8;
typedef __attribute__((ext_vector_type(4))) float f32x4;
typedef __attribute__((ext_vector_type(4))) int   i32x4;
typedef __attribute__((ext_vector_type(4))) unsigned short us4;
typedef __attribute__((ext_vector_type(2))) unsigned int u32x2;
typedef unsigned short ushort_t;

static __device__ __forceinline__ f32x4 mfma16(short8 a, short8 b, f32x4 c) {
    return __builtin_amdgcn_mfma_f32_16x16x32_bf16(a, b, c, 0, 0, 0);
}

// pack 2 f32 -> 1 u32 of 2 bf16 (compiler-managed packed convert, RNE)
static __device__ __forceinline__ unsigned int pk2(float a, float b) {
    __hip_bfloat162 h = __float22bfloat162_rn(make_float2(a, b));
    return *reinterpret_cast<unsigned int*>(&h);
}
static __device__ __forceinline__ ushort_t f2bf(float f) {
    unsigned int u = __float_as_uint(f);
    u = (u + 0x7fffu + ((u >> 16) & 1u)) >> 16;
    return (ushort_t)u;
}
// raw v_exp_f32 (2^x); inputs bounded here so no range handling needed
#if __has_builtin(__builtin_amdgcn_exp2f)
static __device__ __forceinline__ float exp2_fast(float x) { return __builtin_amdgcn_exp2f(x); }
#else
static __device__ __forceinline__ float exp2_fast(float x) { return exp2f(x); }
#endif

// ---------------------------------------------------------------------------
// Kernel 0: fold LayerNorm affine into projection weights.
//   W'[o][c] = W[o][c] * gamma[c]  (bf16)
//   bias'[o] = bp[o] + sum_c beta[c] * W[o][c]   (f32)
// ---------------------------------------------------------------------------
__global__ __launch_bounds__(256)
void k_prep(const float* __restrict__ WpL, const float* __restrict__ WpR,
            const float* __restrict__ bpL, const float* __restrict__ bpR,
            const float* __restrict__ nw,  const float* __restrict__ nb,
            ushort_t* __restrict__ Wb, float* __restrict__ bias2)
{
    const int gid = blockIdx.x * 256 + threadIdx.x;  // 0..2047
    const int row = gid >> 2;                        // 0..511 = side*256 + o
    const int q   = gid & 3;
    const int side = row >> 8;
    const int o    = row & 255;
    const float* Wp = side ? WpR : WpL;
    const float* bp = side ? bpR : bpL;
    const float* wr = Wp + (size_t)o * 128 + q * 32;

    float acc = 0.f;
#pragma unroll
    for (int g = 0; g < 4; ++g) {
        const int c = q * 32 + g * 8;
        float4 wa = *(const float4*)(wr + g * 8);
        float4 wb = *(const float4*)(wr + g * 8 + 4);
        float4 ga = *(const float4*)(nw + c);
        float4 gb = *(const float4*)(nw + c + 4);
        float4 ba = *(const float4*)(nb + c);
        float4 bb = *(const float4*)(nb + c + 4);
        acc += wa.x*ba.x + wa.y*ba.y + wa.z*ba.z + wa.w*ba.w
             + wb.x*bb.x + wb.y*bb.y + wb.z*bb.z + wb.w*bb.w;
        u32x2 o0, o1;
        o0[0] = pk2(wa.x*ga.x, wa.y*ga.y);
        o0[1] = pk2(wa.z*ga.z, wa.w*ga.w);
        o1[0] = pk2(wb.x*gb.x, wb.y*gb.y);
        o1[1] = pk2(wb.z*gb.z, wb.w*gb.w);
        *(u32x2*)(Wb + (size_t)row * 128 + c)     = o0;
        *(u32x2*)(Wb + (size_t)row * 128 + c + 4) = o1;
    }
    acc += __shfl_xor(acc, 1);
    acc += __shfl_xor(acc, 2);
    if (q == 0) bias2[row] = bp[o] + acc;
}

// ---------------------------------------------------------------------------
// Kernel 1: fused LayerNorm + KV projection (affine pre-folded into W').
// ---------------------------------------------------------------------------
__global__ __launch_bounds__(256)
void k_ln_proj(const float* __restrict__ featL, const float* __restrict__ featR,
               const ushort_t* __restrict__ Wb, const float* __restrict__ bias2,
               ushort_t* __restrict__ kvL,      ushort_t* __restrict__ kvR)
{
    const int side = blockIdx.y;
    const float* feat = side ? featR : featL;
    const ushort_t* W = Wb + side * 32768;          // [256][128] bf16
    const float* b2   = bias2 + side * 256;
    ushort_t*    kv   = side ? kvR : kvL;

    const int m0  = blockIdx.x * 64;
    const int tid = threadIdx.x;
    const int wid = tid >> 6, lane = tid & 63, l16 = lane & 15, lh = lane >> 4;
    const int wn  = wid * 64;                       // wave's feature slice

    __shared__ ushort_t smem[64 * 260];             // union: Asm then kvS
    ushort_t (*Asm)[136] = (ushort_t (*)[136])smem; // LN'd activations
    ushort_t (*kvS)[260] = (ushort_t (*)[260])smem; // staged output (pad 4)

    // ---- phase 0: feat loads first ----
    const int row = tid >> 2, q = tid & 3;
    const float* fr = feat + (size_t)(m0 + row) * CC + q * 32;
    float x[32];
#pragma unroll
    for (int i = 0; i < 8; ++i) {
        float4 v = *(const float4*)(fr + i * 4);
        x[i*4+0]=v.x; x[i*4+1]=v.y; x[i*4+2]=v.z; x[i*4+3]=v.w;
    }

    // ---- W-fragment + bias loads (resolve under LN compute) ----
    short8 Bf[16];                                  // [kk][tn]
#pragma unroll
    for (int kk = 0; kk < 4; ++kk)
#pragma unroll
        for (int tn = 0; tn < 4; ++tn)
            Bf[kk*4 + tn] = *(const short8*)(W + (size_t)(wn + tn*16 + l16) * CC + kk*32 + lh*8);
    float4 bias[4];
#pragma unroll
    for (int tn = 0; tn < 4; ++tn)
        bias[tn] = *(const float4*)(b2 + wn + tn*16 + lh*4);

    // ---- LayerNorm (no affine): z = (x-mu)*rstd ----
    {
        float s = 0.f, s2 = 0.f;
#pragma unroll
        for (int i = 0; i < 32; ++i) { s += x[i]; s2 += x[i]*x[i]; }
#pragma unroll
        for (int m = 1; m < 4; m <<= 1) { s += __shfl_xor(s, m); s2 += __shfl_xor(s2, m); }
        float mu   = s * (1.f / 128.f);
        float var  = s2 * (1.f / 128.f) - mu * mu;
        float rstd = rsqrtf(var + 1e-5f);
        float a = rstd, bsh = -mu * rstd;
#pragma unroll
        for (int g = 0; g < 4; ++g) {
            i32x4 o;
#pragma unroll
            for (int k = 0; k < 4; ++k)
                o[k] = (int)pk2(x[g*8 + 2*k] * a + bsh, x[g*8 + 2*k + 1] * a + bsh);
            *(i32x4*)&Asm[row][q * 32 + g * 8] = o;
        }
    }
    __syncthreads();

    // ---- MFMA: wave = 64 tokens x 64 features; A from LDS, B from regs ----
    f32x4 acc[4][4];                                // [m-tile][n-frag]
#pragma unroll
    for (int mt = 0; mt < 4; ++mt)
#pragma unroll
        for (int tn = 0; tn < 4; ++tn)
            acc[mt][tn] = (f32x4){0.f, 0.f, 0.f, 0.f};

#pragma unroll
    for (int kk = 0; kk < 4; ++kk) {
        short8 a[4];
#pragma unroll
        for (int mt = 0; mt < 4; ++mt)
            a[mt] = *(const short8*)&Asm[mt*16 + l16][kk*32 + lh*8];
#pragma unroll
        for (int tn = 0; tn < 4; ++tn)
#pragma unroll
            for (int mt = 0; mt < 4; ++mt)
                acc[mt][tn] = mfma16(Bf[kk*4 + tn], a[mt], acc[mt][tn]); // col=token, row=feat
    }
    __syncthreads();   // all Asm reads done before kvS overwrites

    // ---- epilogue: bias + scale -> bf16 -> staged LDS ----
    const float kscale = (side == 0 && wn < 128) ? 0.14426950408889634f : 1.0f;
#pragma unroll
    for (int mt = 0; mt < 4; ++mt)
#pragma unroll
        for (int tn = 0; tn < 4; ++tn) {
            const int r    = mt*16 + l16;                 // token-local
            const int slot = (wn >> 2) + tn*4 + lh;       // 8B slot (feature/4)
            float v0 = (acc[mt][tn][0] + bias[tn].x) * kscale;
            float v1 = (acc[mt][tn][1] + bias[tn].y) * kscale;
            float v2 = (acc[mt][tn][2] + bias[tn].z) * kscale;
            float v3 = (acc[mt][tn][3] + bias[tn].w) * kscale;
            u32x2 wv;
            wv[0] = pk2(v0, v1);
            wv[1] = pk2(v2, v3);
            *(u32x2*)&kvS[r][slot * 4] = wv;
        }
    __syncthreads();

    // ---- coalesced copy-out: per wave 512B contiguous per iteration ----
#pragma unroll
    for (int it = 0; it < 16; ++it) {
        int u = it * 256 + tid;
        int r = u >> 6, sl = u & 63;
        u32x2 wv = *(const u32x2*)&kvS[r][sl * 4];
        *(u32x2*)(kv + (size_t)(m0 + r) * 256 + sl * 4) = wv;
    }
}

// ---------------------------------------------------------------------------
// Kernel 2: attention, one (n, head, dir) per block; 8 waves x 32-row stripes.
//   No-max softmax (|S| bounded): p = exp2(s) via raw v_exp_f32.
//   Denominator via ones-MFMA (sum of the same bf16 P used in PV) -> no
//   per-chunk VALU adds, no final cross-lane reduce.
//   kB/pL: 64B rows, XOR slot swizzle with (row>>1)&3 -> all LDS ops <=2-way.
//   vT: stride 280 (560B, 16B-aligned rows) -> conflict-free b128 reads.
//   LDS 49.9 KB -> 3 blocks/CU.
// ---------------------------------------------------------------------------
template<int BF16OUT>
__global__ __launch_bounds__(512, 4)
void k_attn(const ushort_t* __restrict__ kvL, const ushort_t* __restrict__ kvR,
            float* __restrict__ outFBase, ushort_t* __restrict__ outBBase)
{
    const int bx   = blockIdx.x;
    const int work = (bx & 7) * 512 + (bx >> 3);    // 4096 = 8 chunks x 512
    const int n    = work >> 3;
    const int e    = (work >> 1) & 3;
    const int dir  = work & 1;
    const ushort_t* kvA = dir ? kvR : kvL;
    const ushort_t* kvB = dir ? kvL : kvR;

    const int tid = threadIdx.x;
    const int wid = tid >> 6, lane = tid & 63, l16 = lane & 15, lh = lane >> 4;
    const int W0 = wid * 32;
    const int kcls = (l16 >> 1) & 3;                // swizzle class of this lane's rows

    __shared__ ushort_t kB[256][32];     // keys of B side, swizzled 64B rows
    __shared__ ushort_t vT[32][280];     // V transposed [c][v], 16B-aligned rows
    __shared__ ushort_t pL[8][32][32];   // wave-private P chunk, swizzled

    // ---- stage kB (swizzled: 16B slot ^= (row>>1)&3) ----
    {
        const ushort_t* src = kvB + (size_t)n * 256 * 256 + e * 32;
#pragma unroll
        for (int p = 0; p < 2; ++p) {
            int u = tid + p * 512;
            int r = u >> 2, slot = u & 3;
            *(i32x4*)&kB[r][(slot ^ ((r >> 1) & 3)) << 3] =
                *(const i32x4*)(src + (size_t)r * 256 + slot * 8);
        }
    }
    // ---- stage vT (transpose via u32 repack) ----
    {
        const ushort_t* src = kvB + (size_t)n * 256 * 256 + 128 + e * 32;
#pragma unroll
        for (int u4 = 0; u4 < 4; ++u4) {
            int unit = tid + u4 * 512;              // 2048 = 16 c-pairs x 128 v-pairs
            int cp = unit & 15, vp = unit >> 4;
            unsigned int w0 = *(const unsigned int*)(src + (size_t)(vp*2    ) * 256 + cp*2);
            unsigned int w1 = *(const unsigned int*)(src + (size_t)(vp*2 + 1) * 256 + cp*2);
            *(unsigned int*)&vT[cp*2    ][vp*2] = (w0 & 0xffffu) | (w1 << 16);
            *(unsigned int*)&vT[cp*2 + 1][vp*2] = (w0 >> 16) | (w1 & 0xffff0000u);
        }
    }
    // ---- kA fragments direct from global ----
    short8 aK[2];
#pragma unroll
    for (int tr = 0; tr < 2; ++tr)
        aK[tr] = *(const short8*)(kvA + (size_t)(n*256 + W0 + tr*16 + l16) * 256 + e*32 + lh*8);

    // ---- ones A-fragment for the denominator MFMA ----
    short8 ones;
#pragma unroll
    for (int i = 0; i < 8; ++i) ones[i] = (short)0x3F80;   // bf16 1.0

    __syncthreads();

    f32x4 oacc[2][2];
#pragma unroll
    for (int tr = 0; tr < 2; ++tr)
#pragma unroll
        for (int ct = 0; ct < 2; ++ct)
            oacc[tr][ct] = (f32x4){0.f, 0.f, 0.f, 0.f};
    f32x4 lacc[2] = {(f32x4){0.f,0.f,0.f,0.f}, (f32x4){0.f,0.f,0.f,0.f}};

#pragma unroll 2
    for (int nc = 0; nc < 8; ++nc) {
        const int vc0 = nc * 32;

        // ---- QK chunk: S[w, vc0..vc0+31] (swizzled kB read) ----
        short8 bk0 = *(const short8*)&kB[vc0      + l16][(lh ^ kcls) << 3];
        short8 bk1 = *(const short8*)&kB[vc0 + 16 + l16][(lh ^ kcls) << 3];
        f32x4 s[2][2];
#pragma unroll
        for (int tr = 0; tr < 2; ++tr) {
            s[tr][0] = mfma16(bk0, aK[tr], (f32x4){0.f,0.f,0.f,0.f});
            s[tr][1] = mfma16(bk1, aK[tr], (f32x4){0.f,0.f,0.f,0.f});
        }

        // ---- p = exp2(s); pack -> pL (swizzled, <=2-way writes) ----
#pragma unroll
        for (int tr = 0; tr < 2; ++tr) {
            const int prow = tr*16 + l16;
#pragma unroll
            for (int tc = 0; tc < 2; ++tc) {
                float p0 = exp2_fast(s[tr][tc][0]);
                float p1 = exp2_fast(s[tr][tc][1]);
                float p2 = exp2_fast(s[tr][tc][2]);
                float p3 = exp2_fast(s[tr][tc][3]);
                u32x2 w;
                w[0] = pk2(p0, p1);
                w[1] = pk2(p2, p3);
                const int sL   = 2*tc + (lh >> 1);
                const int pcol = ((sL ^ kcls) << 3) + ((lh & 1) << 2);
                *(u32x2*)&pL[wid][prow][pcol] = w;
            }
        }

        // ---- PV + denominator for this 32-wide k-slice ----
        short8 aP[2], bV[2];
#pragma unroll
        for (int tr = 0; tr < 2; ++tr)
            aP[tr] = *(const short8*)&pL[wid][tr*16 + l16][(lh ^ kcls) << 3];
#pragma unroll
        for (int ct = 0; ct < 2; ++ct)
            bV[ct] = *(const short8*)&vT[ct*16 + l16][vc0 + lh*8];
#pragma unroll
        for (int tr = 0; tr < 2; ++tr) {
#pragma unroll
            for (int ct = 0; ct < 2; ++ct)
                oacc[tr][ct] = mfma16(bV[ct], aP[tr], oacc[tr][ct]); // col=w, row=c
            lacc[tr] = mfma16(ones, aP[tr], lacc[tr]);               // col=w, row: all = sum
        }
    }

    // ---- normalize + store (denominator already per-lane complete) ----
#pragma unroll
    for (int tr = 0; tr < 2; ++tr) {
        float rinv = 1.f / lacc[tr][0];
        const int token = n * 256 + W0 + tr*16 + l16;
        if (BF16OUT) {
            ushort_t* outB = outBBase + (size_t)dir * TOK * CC;
#pragma unroll
            for (int ct = 0; ct < 2; ++ct) {
                us4 o;
#pragma unroll
                for (int j = 0; j < 4; ++j)
                    o[j] = f2bf(oacc[tr][ct][j] * rinv);
                *(us4*)(outB + (size_t)token * CC + e*32 + ct*16 + lh*4) = o;
            }
        } else {
            float* outF = outFBase + (size_t)dir * TOK * CC;
#pragma unroll
            for (int ct = 0; ct < 2; ++ct) {
                float4 o;
                o.x = oacc[tr][ct][0] * rinv;
                o.y = oacc[tr][ct][1] * rinv;
                o.z = oacc[tr][ct][2] * rinv;
                o.w = oacc[tr][ct][3] * rinv;
                *(float4*)(outF + (size_t)token * CC + e*32 + ct*16 + lh*4) = o;
            }
        }
    }
}

// ---------------------------------------------------------------------------
// Kernel 3: out projection + bias + residual -> d_out (f32).
// ---------------------------------------------------------------------------
template<int BF16IN>
__global__ __launch_bounds__(512, 4)
void k_outproj(float* __restrict__ outBase, const ushort_t* __restrict__ aoutBase,
               const float* __restrict__ featL, const float* __restrict__ featR,
               const float* __restrict__ WoL,   const float* __restrict__ WoR,
               const float* __restrict__ boL,   const float* __restrict__ boR)
{
    const int side = blockIdx.y;
    float* io = outBase + (size_t)side * TOK * CC;
    const float* feat = side ? featR : featL;
    const float* Wo   = side ? WoR   : WoL;
    const float* bo   = side ? boR   : boL;

    const int m0 = blockIdx.x * 64;
    const int tid = threadIdx.x;

    __shared__ ushort_t Asm[64][136];
    __shared__ ushort_t Wsm[128][136];

#pragma unroll
    for (int i = 0; i < 8; ++i) {
        int u = tid + i * 512;
        int r = u >> 5, c4 = (u & 31) * 4;
        float4 w4 = *(const float4*)(Wo + (size_t)r * CC + c4);
        Wsm[r][c4+0] = f2bf(w4.x); Wsm[r][c4+1] = f2bf(w4.y);
        Wsm[r][c4+2] = f2bf(w4.z); Wsm[r][c4+3] = f2bf(w4.w);
    }
    if (BF16IN) {
        const ushort_t* src = aoutBase + (size_t)side * TOK * CC;
#pragma unroll
        for (int i = 0; i < 2; ++i) {
            int u = tid + i * 512;
            int r = u >> 4, c0 = (u & 15) * 8;
            *(i32x4*)&Asm[r][c0] = *(const i32x4*)(src + (size_t)(m0 + r) * CC + c0);
        }
    } else {
#pragma unroll
        for (int i = 0; i < 4; ++i) {
            int u = tid + i * 512;
            int r = u >> 5, c4 = (u & 31) * 4;
            float4 a4 = *(const float4*)(io + (size_t)(m0 + r) * CC + c4);
            Asm[r][c4+0] = f2bf(a4.x); Asm[r][c4+1] = f2bf(a4.y);
            Asm[r][c4+2] = f2bf(a4.z); Asm[r][c4+3] = f2bf(a4.w);
        }
    }
    __syncthreads();

    const int wid = tid >> 6, lane = tid & 63, l16 = lane & 15, lh = lane >> 4;
    const int wm = (wid >> 2) * 32;
    const int wn = (wid & 3) * 32;
    f32x4 acc[2][2];
#pragma unroll
    for (int tr = 0; tr < 2; ++tr)
#pragma unroll
        for (int nt = 0; nt < 2; ++nt)
            acc[tr][nt] = (f32x4){0.f, 0.f, 0.f, 0.f};

#pragma unroll
    for (int kk = 0; kk < 4; ++kk) {
        short8 a[2], b[2];
#pragma unroll
        for (int tr = 0; tr < 2; ++tr)
            a[tr] = *(const short8*)&Asm[wm + tr*16 + l16][kk*32 + lh*8];
#pragma unroll
        for (int nt = 0; nt < 2; ++nt)
            b[nt] = *(const short8*)&Wsm[wn + nt*16 + l16][kk*32 + lh*8];
#pragma unroll
        for (int tr = 0; tr < 2; ++tr)
#pragma unroll
            for (int nt = 0; nt < 2; ++nt)
                acc[tr][nt] = mfma16(a[tr], b[nt], acc[tr][nt]);
    }

#pragma unroll
    for (int tr = 0; tr < 2; ++tr)
#pragma unroll
        for (int nt = 0; nt < 2; ++nt) {
            int c = wn + nt*16 + l16;
            float bias = bo[c];
#pragma unroll
            for (int j = 0; j < 4; ++j) {
                int r = m0 + wm + tr*16 + lh*4 + j;
                io[(size_t)r * CC + c] = acc[tr][nt][j] + bias + feat[(size_t)r * CC + c];
            }
        }
}

// ---------------------------------------------------------------------------
extern "C" void kernel_launch(void* const* d_in, const int* in_sizes, int n_in,
                              void* d_out, int out_size, void* d_ws, size_t ws_size,
                              hipStream_t stream)
{
    const float* featL = (const float*)d_in[0];
    const float* featR = (const float*)d_in[1];
    const float* WpL   = (const float*)d_in[2];
    const float* WpR   = (const float*)d_in[3];
    const float* bpL   = (const float*)d_in[4];
    const float* bpR   = (const float*)d_in[5];
    const float* WoL   = (const float*)d_in[6];
    const float* boL   = (const float*)d_in[7];
    const float* WoR   = (const float*)d_in[8];
    const float* boR   = (const float*)d_in[9];
    const float* nw    = (const float*)d_in[10];
    const float* nb    = (const float*)d_in[11];

    float* out = (float*)d_out;
    ushort_t* kvL = (ushort_t*)d_ws;                 // [TOK][256] bf16
    ushort_t* kvR = kvL + (size_t)TOK * 256;         // [TOK][256] bf16
    ushort_t* aout = kvR + (size_t)TOK * 256;        // [2][TOK][128] bf16 (optional)
    ushort_t* Wb  = (ushort_t*)d_out;                // W' bf16 [2][256][128]
    float* bias2  = (float*)d_out + 32768;           // bias' f32 [2][256]

    const size_t need_bf16 = (size_t)TOK * 256 * 2 * 2 + (size_t)TOK * CC * 2 * 2;
    const bool bf16path = ws_size >= need_bf16;

    k_prep<<<dim3(8), 256, 0, stream>>>(WpL, WpR, bpL, bpR, nw, nb, Wb, bias2);
    k_ln_proj<<<dim3(2048, 2), 256, 0, stream>>>(featL, featR, Wb, bias2, kvL, kvR);
    if (bf16path) {
        k_attn<1><<<dim3(4096), 512, 0, stream>>>(kvL, kvR, out, aout);
        k_outproj<1><<<dim3(TOK / 64, 2), 512, 0, stream>>>(out, aout, featL, featR,
                                                            WoL, WoR, boL, boR);
    } else {
        k_attn<0><<<dim3(4096), 512, 0, stream>>>(kvL, kvR, out, aout);
        k_outproj<0><<<dim3(TOK / 64, 2), 512, 0, stream>>>(out, aout, featL, featR,
                                                            WoL, WoR, boL, boR);
    }
}

// Round 9
// 200.446 us; speedup vs baseline: 2.6830x; 1.0688x over previous
//
#include <hip/hip_runtime.h>
#include <hip/hip_bf16.h>

#define BH   512
#define NW   256
#define CC   128
#define TOK  (BH * NW)   // 131072 tokens per side

typedef __attribute__((ext_vector_type(8))) short short8;
typedef __attribute__((ext_vector_type(4))) float f32x4;
typedef __attribute__((ext_vector_type(4))) int   i32x4;
typedef __attribute__((ext_vector_type(4))) unsigned short us4;
typedef __attribute__((ext_vector_type(2))) unsigned int u32x2;
typedef unsigned short ushort_t;

static __device__ __forceinline__ f32x4 mfma16(short8 a, short8 b, f32x4 c) {
    return __builtin_amdgcn_mfma_f32_16x16x32_bf16(a, b, c, 0, 0, 0);
}

// pack 2 f32 -> 1 u32 of 2 bf16 (compiler-managed packed convert, RNE)
static __device__ __forceinline__ unsigned int pk2(float a, float b) {
    __hip_bfloat162 h = __float22bfloat162_rn(make_float2(a, b));
    return *reinterpret_cast<unsigned int*>(&h);
}
static __device__ __forceinline__ ushort_t f2bf(float f) {
    unsigned int u = __float_as_uint(f);
    u = (u + 0x7fffu + ((u >> 16) & 1u)) >> 16;
    return (ushort_t)u;
}
// raw v_exp_f32 (2^x); inputs bounded here so no range handling needed
#if __has_builtin(__builtin_amdgcn_exp2f)
static __device__ __forceinline__ float exp2_fast(float x) { return __builtin_amdgcn_exp2f(x); }
#else
static __device__ __forceinline__ float exp2_fast(float x) { return exp2f(x); }
#endif

// ---------------------------------------------------------------------------
// Kernel 0: fold LayerNorm affine into projection weights.
//   W'[o][c] = W[o][c] * gamma[c]  (bf16)
//   bias'[o] = bp[o] + sum_c beta[c] * W[o][c]   (f32)
// ---------------------------------------------------------------------------
__global__ __launch_bounds__(256)
void k_prep(const float* __restrict__ WpL, const float* __restrict__ WpR,
            const float* __restrict__ bpL, const float* __restrict__ bpR,
            const float* __restrict__ nw,  const float* __restrict__ nb,
            ushort_t* __restrict__ Wb, float* __restrict__ bias2)
{
    const int gid = blockIdx.x * 256 + threadIdx.x;  // 0..2047
    const int row = gid >> 2;                        // 0..511 = side*256 + o
    const int q   = gid & 3;
    const int side = row >> 8;
    const int o    = row & 255;
    const float* Wp = side ? WpR : WpL;
    const float* bp = side ? bpR : bpL;
    const float* wr = Wp + (size_t)o * 128 + q * 32;

    float acc = 0.f;
#pragma unroll
    for (int g = 0; g < 4; ++g) {
        const int c = q * 32 + g * 8;
        float4 wa = *(const float4*)(wr + g * 8);
        float4 wb = *(const float4*)(wr + g * 8 + 4);
        float4 ga = *(const float4*)(nw + c);
        float4 gb = *(const float4*)(nw + c + 4);
        float4 ba = *(const float4*)(nb + c);
        float4 bb = *(const float4*)(nb + c + 4);
        acc += wa.x*ba.x + wa.y*ba.y + wa.z*ba.z + wa.w*ba.w
             + wb.x*bb.x + wb.y*bb.y + wb.z*bb.z + wb.w*bb.w;
        u32x2 o0, o1;
        o0[0] = pk2(wa.x*ga.x, wa.y*ga.y);
        o0[1] = pk2(wa.z*ga.z, wa.w*ga.w);
        o1[0] = pk2(wb.x*gb.x, wb.y*gb.y);
        o1[1] = pk2(wb.z*gb.z, wb.w*gb.w);
        *(u32x2*)(Wb + (size_t)row * 128 + c)     = o0;
        *(u32x2*)(Wb + (size_t)row * 128 + c + 4) = o1;
    }
    acc += __shfl_xor(acc, 1);
    acc += __shfl_xor(acc, 2);
    if (q == 0) bias2[row] = bp[o] + acc;
}

// ---------------------------------------------------------------------------
// Kernel 1: fused LayerNorm + KV projection (affine pre-folded into W').
//   512 thr = 8 waves; tile 64 tokens x 256 features; wave = 64 tok x 32 feat.
//   Register budget: Bf[8]=32 VGPR + acc[4][2]=32 AGPR + x[16] -> ~105 unified
//   => 4 waves/SIMD (occupancy doubled vs round-8's 64-feature waves).
// ---------------------------------------------------------------------------
__global__ __launch_bounds__(512)
void k_ln_proj(const float* __restrict__ featL, const float* __restrict__ featR,
               const ushort_t* __restrict__ Wb, const float* __restrict__ bias2,
               ushort_t* __restrict__ kvL,      ushort_t* __restrict__ kvR)
{
    const int side = blockIdx.y;
    const float* feat = side ? featR : featL;
    const ushort_t* W = Wb + side * 32768;          // [256][128] bf16
    const float* b2   = bias2 + side * 256;
    ushort_t*    kv   = side ? kvR : kvL;

    const int m0  = blockIdx.x * 64;
    const int tid = threadIdx.x;
    const int wid = tid >> 6, lane = tid & 63, l16 = lane & 15, lh = lane >> 4;
    const int wn  = wid * 32;                       // wave's feature slice

    __shared__ ushort_t smem[64 * 260];             // union: Asm then kvS
    ushort_t (*Asm)[136] = (ushort_t (*)[136])smem; // LN'd activations
    ushort_t (*kvS)[260] = (ushort_t (*)[260])smem; // staged output (pad 4)

    // ---- phase 0: feat loads first (HBM long pole) ----
    const int row = tid >> 3, q = tid & 7;          // 8 threads/row, 16 elems
    const float* fr = feat + (size_t)(m0 + row) * CC + q * 16;
    float x[16];
#pragma unroll
    for (int i = 0; i < 4; ++i) {
        float4 v = *(const float4*)(fr + i * 4);
        x[i*4+0]=v.x; x[i*4+1]=v.y; x[i*4+2]=v.z; x[i*4+3]=v.w;
    }

    // ---- W-fragment + bias loads (resolve under LN compute) ----
    short8 Bf[8];                                   // [kk][tn], tn=0..1
#pragma unroll
    for (int kk = 0; kk < 4; ++kk)
#pragma unroll
        for (int tn = 0; tn < 2; ++tn)
            Bf[kk*2 + tn] = *(const short8*)(W + (size_t)(wn + tn*16 + l16) * CC + kk*32 + lh*8);
    float4 bias[2];
#pragma unroll
    for (int tn = 0; tn < 2; ++tn)
        bias[tn] = *(const float4*)(b2 + wn + tn*16 + lh*4);

    // ---- LayerNorm (no affine): z = (x-mu)*rstd ----
    {
        float s = 0.f, s2 = 0.f;
#pragma unroll
        for (int i = 0; i < 16; ++i) { s += x[i]; s2 += x[i]*x[i]; }
#pragma unroll
        for (int m = 1; m < 8; m <<= 1) { s += __shfl_xor(s, m); s2 += __shfl_xor(s2, m); }
        float mu   = s * (1.f / 128.f);
        float var  = s2 * (1.f / 128.f) - mu * mu;
        float rstd = rsqrtf(var + 1e-5f);
        float a = rstd, bsh = -mu * rstd;
#pragma unroll
        for (int g = 0; g < 2; ++g) {
            i32x4 o;
#pragma unroll
            for (int k = 0; k < 4; ++k)
                o[k] = (int)pk2(x[g*8 + 2*k] * a + bsh, x[g*8 + 2*k + 1] * a + bsh);
            *(i32x4*)&Asm[row][q * 16 + g * 8] = o;
        }
    }
    __syncthreads();

    // ---- MFMA: wave = 64 tokens x 32 features; A from LDS, B from regs ----
    f32x4 acc[4][2];                                // [m-tile][n-frag]
#pragma unroll
    for (int mt = 0; mt < 4; ++mt)
#pragma unroll
        for (int tn = 0; tn < 2; ++tn)
            acc[mt][tn] = (f32x4){0.f, 0.f, 0.f, 0.f};

#pragma unroll
    for (int kk = 0; kk < 4; ++kk) {
        short8 a[4];
#pragma unroll
        for (int mt = 0; mt < 4; ++mt)
            a[mt] = *(const short8*)&Asm[mt*16 + l16][kk*32 + lh*8];
#pragma unroll
        for (int tn = 0; tn < 2; ++tn)
#pragma unroll
            for (int mt = 0; mt < 4; ++mt)
                acc[mt][tn] = mfma16(Bf[kk*2 + tn], a[mt], acc[mt][tn]); // col=token, row=feat
    }
    __syncthreads();   // all Asm reads done before kvS overwrites

    // ---- epilogue: bias + scale -> bf16 -> staged LDS ----
    const float kscale = (side == 0 && wn < 128) ? 0.14426950408889634f : 1.0f;
#pragma unroll
    for (int mt = 0; mt < 4; ++mt)
#pragma unroll
        for (int tn = 0; tn < 2; ++tn) {
            const int r    = mt*16 + l16;                 // token-local
            const int slot = (wn >> 2) + tn*4 + lh;       // 8B slot (feature/4)
            float v0 = (acc[mt][tn][0] + bias[tn].x) * kscale;
            float v1 = (acc[mt][tn][1] + bias[tn].y) * kscale;
            float v2 = (acc[mt][tn][2] + bias[tn].z) * kscale;
            float v3 = (acc[mt][tn][3] + bias[tn].w) * kscale;
            u32x2 wv;
            wv[0] = pk2(v0, v1);
            wv[1] = pk2(v2, v3);
            *(u32x2*)&kvS[r][slot * 4] = wv;
        }
    __syncthreads();

    // ---- coalesced copy-out: 512B contiguous per wave-iteration ----
#pragma unroll
    for (int it = 0; it < 8; ++it) {
        int u = it * 512 + tid;
        int r = u >> 6, sl = u & 63;
        u32x2 wv = *(const u32x2*)&kvS[r][sl * 4];
        *(u32x2*)(kv + (size_t)(m0 + r) * 256 + sl * 4) = wv;
    }
}

// ---------------------------------------------------------------------------
// Kernel 2: attention, one (n, head, dir) per block; 8 waves x 32-row stripes.
//   No-max softmax (|S| bounded): p = exp2(s) via raw v_exp_f32.
//   Denominator via ones-MFMA; kB/pL XOR slot swizzle with (row>>1)&3;
//   vT stride 280 (16B-aligned rows). LDS 49.9 KB -> 3 blocks/CU.
// ---------------------------------------------------------------------------
template<int BF16OUT>
__global__ __launch_bounds__(512, 4)
void k_attn(const ushort_t* __restrict__ kvL, const ushort_t* __restrict__ kvR,
            float* __restrict__ outFBase, ushort_t* __restrict__ outBBase)
{
    const int bx   = blockIdx.x;
    const int work = (bx & 7) * 512 + (bx >> 3);    // 4096 = 8 chunks x 512
    const int n    = work >> 3;
    const int e    = (work >> 1) & 3;
    const int dir  = work & 1;
    const ushort_t* kvA = dir ? kvR : kvL;
    const ushort_t* kvB = dir ? kvL : kvR;

    const int tid = threadIdx.x;
    const int wid = tid >> 6, lane = tid & 63, l16 = lane & 15, lh = lane >> 4;
    const int W0 = wid * 32;
    const int kcls = (l16 >> 1) & 3;                // swizzle class of this lane's rows

    __shared__ ushort_t kB[256][32];     // keys of B side, swizzled 64B rows
    __shared__ ushort_t vT[32][280];     // V transposed [c][v], 16B-aligned rows
    __shared__ ushort_t pL[8][32][32];   // wave-private P chunk, swizzled

    // ---- stage kB (swizzled: 16B slot ^= (row>>1)&3) ----
    {
        const ushort_t* src = kvB + (size_t)n * 256 * 256 + e * 32;
#pragma unroll
        for (int p = 0; p < 2; ++p) {
            int u = tid + p * 512;
            int r = u >> 2, slot = u & 3;
            *(i32x4*)&kB[r][(slot ^ ((r >> 1) & 3)) << 3] =
                *(const i32x4*)(src + (size_t)r * 256 + slot * 8);
        }
    }
    // ---- stage vT (transpose via u32 repack) ----
    {
        const ushort_t* src = kvB + (size_t)n * 256 * 256 + 128 + e * 32;
#pragma unroll
        for (int u4 = 0; u4 < 4; ++u4) {
            int unit = tid + u4 * 512;              // 2048 = 16 c-pairs x 128 v-pairs
            int cp = unit & 15, vp = unit >> 4;
            unsigned int w0 = *(const unsigned int*)(src + (size_t)(vp*2    ) * 256 + cp*2);
            unsigned int w1 = *(const unsigned int*)(src + (size_t)(vp*2 + 1) * 256 + cp*2);
            *(unsigned int*)&vT[cp*2    ][vp*2] = (w0 & 0xffffu) | (w1 << 16);
            *(unsigned int*)&vT[cp*2 + 1][vp*2] = (w0 >> 16) | (w1 & 0xffff0000u);
        }
    }
    // ---- kA fragments direct from global ----
    short8 aK[2];
#pragma unroll
    for (int tr = 0; tr < 2; ++tr)
        aK[tr] = *(const short8*)(kvA + (size_t)(n*256 + W0 + tr*16 + l16) * 256 + e*32 + lh*8);

    // ---- ones A-fragment for the denominator MFMA ----
    short8 ones;
#pragma unroll
    for (int i = 0; i < 8; ++i) ones[i] = (short)0x3F80;   // bf16 1.0

    __syncthreads();

    f32x4 oacc[2][2];
#pragma unroll
    for (int tr = 0; tr < 2; ++tr)
#pragma unroll
        for (int ct = 0; ct < 2; ++ct)
            oacc[tr][ct] = (f32x4){0.f, 0.f, 0.f, 0.f};
    f32x4 lacc[2] = {(f32x4){0.f,0.f,0.f,0.f}, (f32x4){0.f,0.f,0.f,0.f}};

#pragma unroll 2
    for (int nc = 0; nc < 8; ++nc) {
        const int vc0 = nc * 32;

        // ---- QK chunk: S[w, vc0..vc0+31] (swizzled kB read) ----
        short8 bk0 = *(const short8*)&kB[vc0      + l16][(lh ^ kcls) << 3];
        short8 bk1 = *(const short8*)&kB[vc0 + 16 + l16][(lh ^ kcls) << 3];
        f32x4 s[2][2];
#pragma unroll
        for (int tr = 0; tr < 2; ++tr) {
            s[tr][0] = mfma16(bk0, aK[tr], (f32x4){0.f,0.f,0.f,0.f});
            s[tr][1] = mfma16(bk1, aK[tr], (f32x4){0.f,0.f,0.f,0.f});
        }

        // ---- p = exp2(s); pack -> pL (swizzled, <=2-way writes) ----
#pragma unroll
        for (int tr = 0; tr < 2; ++tr) {
            const int prow = tr*16 + l16;
#pragma unroll
            for (int tc = 0; tc < 2; ++tc) {
                float p0 = exp2_fast(s[tr][tc][0]);
                float p1 = exp2_fast(s[tr][tc][1]);
                float p2 = exp2_fast(s[tr][tc][2]);
                float p3 = exp2_fast(s[tr][tc][3]);
                u32x2 w;
                w[0] = pk2(p0, p1);
                w[1] = pk2(p2, p3);
                const int sL   = 2*tc + (lh >> 1);
                const int pcol = ((sL ^ kcls) << 3) + ((lh & 1) << 2);
                *(u32x2*)&pL[wid][prow][pcol] = w;
            }
        }

        // ---- PV + denominator for this 32-wide k-slice ----
        short8 aP[2], bV[2];
#pragma unroll
        for (int tr = 0; tr < 2; ++tr)
            aP[tr] = *(const short8*)&pL[wid][tr*16 + l16][(lh ^ kcls) << 3];
#pragma unroll
        for (int ct = 0; ct < 2; ++ct)
            bV[ct] = *(const short8*)&vT[ct*16 + l16][vc0 + lh*8];
#pragma unroll
        for (int tr = 0; tr < 2; ++tr) {
#pragma unroll
            for (int ct = 0; ct < 2; ++ct)
                oacc[tr][ct] = mfma16(bV[ct], aP[tr], oacc[tr][ct]); // col=w, row=c
            lacc[tr] = mfma16(ones, aP[tr], lacc[tr]);               // col=w, row: all = sum
        }
    }

    // ---- normalize + store (denominator already per-lane complete) ----
#pragma unroll
    for (int tr = 0; tr < 2; ++tr) {
        float rinv = 1.f / lacc[tr][0];
        const int token = n * 256 + W0 + tr*16 + l16;
        if (BF16OUT) {
            ushort_t* outB = outBBase + (size_t)dir * TOK * CC;
#pragma unroll
            for (int ct = 0; ct < 2; ++ct) {
                us4 o;
#pragma unroll
                for (int j = 0; j < 4; ++j)
                    o[j] = f2bf(oacc[tr][ct][j] * rinv);
                *(us4*)(outB + (size_t)token * CC + e*32 + ct*16 + lh*4) = o;
            }
        } else {
            float* outF = outFBase + (size_t)dir * TOK * CC;
#pragma unroll
            for (int ct = 0; ct < 2; ++ct) {
                float4 o;
                o.x = oacc[tr][ct][0] * rinv;
                o.y = oacc[tr][ct][1] * rinv;
                o.z = oacc[tr][ct][2] * rinv;
                o.w = oacc[tr][ct][3] * rinv;
                *(float4*)(outF + (size_t)token * CC + e*32 + ct*16 + lh*4) = o;
            }
        }
    }
}

// ---------------------------------------------------------------------------
// Kernel 3: out projection + bias + residual -> d_out (f32).
// ---------------------------------------------------------------------------
template<int BF16IN>
__global__ __launch_bounds__(512, 4)
void k_outproj(float* __restrict__ outBase, const ushort_t* __restrict__ aoutBase,
               const float* __restrict__ featL, const float* __restrict__ featR,
               const float* __restrict__ WoL,   const float* __restrict__ WoR,
               const float* __restrict__ boL,   const float* __restrict__ boR)
{
    const int side = blockIdx.y;
    float* io = outBase + (size_t)side * TOK * CC;
    const float* feat = side ? featR : featL;
    const float* Wo   = side ? WoR   : WoL;
    const float* bo   = side ? boR   : boL;

    const int m0 = blockIdx.x * 64;
    const int tid = threadIdx.x;

    __shared__ ushort_t Asm[64][136];
    __shared__ ushort_t Wsm[128][136];

#pragma unroll
    for (int i = 0; i < 8; ++i) {
        int u = tid + i * 512;
        int r = u >> 5, c4 = (u & 31) * 4;
        float4 w4 = *(const float4*)(Wo + (size_t)r * CC + c4);
        Wsm[r][c4+0] = f2bf(w4.x); Wsm[r][c4+1] = f2bf(w4.y);
        Wsm[r][c4+2] = f2bf(w4.z); Wsm[r][c4+3] = f2bf(w4.w);
    }
    if (BF16IN) {
        const ushort_t* src = aoutBase + (size_t)side * TOK * CC;
#pragma unroll
        for (int i = 0; i < 2; ++i) {
            int u = tid + i * 512;
            int r = u >> 4, c0 = (u & 15) * 8;
            *(i32x4*)&Asm[r][c0] = *(const i32x4*)(src + (size_t)(m0 + r) * CC + c0);
        }
    } else {
#pragma unroll
        for (int i = 0; i < 4; ++i) {
            int u = tid + i * 512;
            int r = u >> 5, c4 = (u & 31) * 4;
            float4 a4 = *(const float4*)(io + (size_t)(m0 + r) * CC + c4);
            Asm[r][c4+0] = f2bf(a4.x); Asm[r][c4+1] = f2bf(a4.y);
            Asm[r][c4+2] = f2bf(a4.z); Asm[r][c4+3] = f2bf(a4.w);
        }
    }
    __syncthreads();

    const int wid = tid >> 6, lane = tid & 63, l16 = lane & 15, lh = lane >> 4;
    const int wm = (wid >> 2) * 32;
    const int wn = (wid & 3) * 32;
    f32x4 acc[2][2];
#pragma unroll
    for (int tr = 0; tr < 2; ++tr)
#pragma unroll
        for (int nt = 0; nt < 2; ++nt)
            acc[tr][nt] = (f32x4){0.f, 0.f, 0.f, 0.f};

#pragma unroll
    for (int kk = 0; kk < 4; ++kk) {
        short8 a[2], b[2];
#pragma unroll
        for (int tr = 0; tr < 2; ++tr)
            a[tr] = *(const short8*)&Asm[wm + tr*16 + l16][kk*32 + lh*8];
#pragma unroll
        for (int nt = 0; nt < 2; ++nt)
            b[nt] = *(const short8*)&Wsm[wn + nt*16 + l16][kk*32 + lh*8];
#pragma unroll
        for (int tr = 0; tr < 2; ++tr)
#pragma unroll
            for (int nt = 0; nt < 2; ++nt)
                acc[tr][nt] = mfma16(a[tr], b[nt], acc[tr][nt]);
    }

#pragma unroll
    for (int tr = 0; tr < 2; ++tr)
#pragma unroll
        for (int nt = 0; nt < 2; ++nt) {
            int c = wn + nt*16 + l16;
            float bias = bo[c];
#pragma unroll
            for (int j = 0; j < 4; ++j) {
                int r = m0 + wm + tr*16 + lh*4 + j;
                io[(size_t)r * CC + c] = acc[tr][nt][j] + bias + feat[(size_t)r * CC + c];
            }
        }
}

// ---------------------------------------------------------------------------
extern "C" void kernel_launch(void* const* d_in, const int* in_sizes, int n_in,
                              void* d_out, int out_size, void* d_ws, size_t ws_size,
                              hipStream_t stream)
{
    const float* featL = (const float*)d_in[0];
    const float* featR = (const float*)d_in[1];
    const float* WpL   = (const float*)d_in[2];
    const float* WpR   = (const float*)d_in[3];
    const float* bpL   = (const float*)d_in[4];
    const float* bpR   = (const float*)d_in[5];
    const float* WoL   = (const float*)d_in[6];
    const float* boL   = (const float*)d_in[7];
    const float* WoR   = (const float*)d_in[8];
    const float* boR   = (const float*)d_in[9];
    const float* nw    = (const float*)d_in[10];
    const float* nb    = (const float*)d_in[11];

    float* out = (float*)d_out;
    ushort_t* kvL = (ushort_t*)d_ws;                 // [TOK][256] bf16
    ushort_t* kvR = kvL + (size_t)TOK * 256;         // [TOK][256] bf16
    ushort_t* aout = kvR + (size_t)TOK * 256;        // [2][TOK][128] bf16 (optional)
    ushort_t* Wb  = (ushort_t*)d_out;                // W' bf16 [2][256][128]
    float* bias2  = (float*)d_out + 32768;           // bias' f32 [2][256]

    const size_t need_bf16 = (size_t)TOK * 256 * 2 * 2 + (size_t)TOK * CC * 2 * 2;
    const bool bf16path = ws_size >= need_bf16;

    k_prep<<<dim3(8), 256, 0, stream>>>(WpL, WpR, bpL, bpR, nw, nb, Wb, bias2);
    k_ln_proj<<<dim3(2048, 2), 512, 0, stream>>>(featL, featR, Wb, bias2, kvL, kvR);
    if (bf16path) {
        k_attn<1><<<dim3(4096), 512, 0, stream>>>(kvL, kvR, out, aout);
        k_outproj<1><<<dim3(TOK / 64, 2), 512, 0, stream>>>(out, aout, featL, featR,
                                                            WoL, WoR, boL, boR);
    } else {
        k_attn<0><<<dim3(4096), 512, 0, stream>>>(kvL, kvR, out, aout);
        k_outproj<0><<<dim3(TOK / 64, 2), 512, 0, stream>>>(out, aout, featL, featR,
                                                            WoL, WoR, boL, boR);
    }
}